// Round 6
// baseline (2681.383 us; speedup 1.0000x reference)
//
#include <hip/hip_runtime.h>

typedef unsigned short u16;
typedef _Float16 f16x8_t __attribute__((ext_vector_type(8)));
typedef short    i16x8_t __attribute__((ext_vector_type(8)));
typedef short    i16x4_t __attribute__((ext_vector_type(4)));
typedef float    f32x4_t __attribute__((ext_vector_type(4)));

// force a loaded value to stay materialized in VGPRs (no remat/sinking)
#define PIN(x) asm volatile("" : "+v"(x))

// ---- helpers ---------------------------------------------------------------
static __device__ __forceinline__ u16 f2h(float f) {
  _Float16 h = (_Float16)f;  // RNE
  return __builtin_bit_cast(u16, h);
}
static __device__ __forceinline__ f32x4_t mfma16h(i16x8_t a, i16x8_t b, f32x4_t c) {
  return __builtin_amdgcn_mfma_f32_16x16x32_f16(
      __builtin_bit_cast(f16x8_t, a), __builtin_bit_cast(f16x8_t, b), c, 0, 0, 0);
}
static __device__ __forceinline__ float sigmoidf_(float x) { return 1.f / (1.f + __expf(-x)); }
static __device__ __forceinline__ float tanhf_(float x) { return 1.f - 2.f / (__expf(2.f * x) + 1.f); }

// ---- prep: LSTM weights pre-swizzled into MFMA fragment order --------------
// wpack[dir][tau][kb][lane][8]: tau = jb*4+g (jb = j-block, g = gate),
// kb in [0,12), lane = quad*16+mrow. Element e: n = g*256+jb*16+mrow,
// k = kb*32+quad*8+e; value = k<128 ? Wi[k][n] : Wh[k-128][n].
__global__ __launch_bounds__(256) void prep_wpack(const float* __restrict__ Wi_f,
                                                  const float* __restrict__ Wh_f,
                                                  const float* __restrict__ Wi_r,
                                                  const float* __restrict__ Wh_r,
                                                  u16* __restrict__ wpack) {
  int id = blockIdx.x * 256 + threadIdx.x;
  if (id >= 786432) return;  // 2*64*12*64*8
  int e = id & 7, r = id >> 3;
  int lane = r & 63; r >>= 6;
  int kb = r % 12; r /= 12;
  int tau = r & 63, dir = r >> 6;
  int mrow = lane & 15, quad = lane >> 4;
  int jb = tau >> 2, g = tau & 3;
  int n = g * 256 + jb * 16 + mrow;
  int k = kb * 32 + quad * 8 + e;
  const float* Wi = dir ? Wi_r : Wi_f;
  const float* Wh = dir ? Wh_r : Wh_f;
  float v = (k < 128) ? Wi[k * 1024 + n] : Wh[(k - 128) * 1024 + n];
  wpack[id] = f2h(v);
}

// ---- prep: MLP W^T in f16 + flag zeroing ----------------------------------
__global__ __launch_bounds__(256) void prep_small(const float* __restrict__ W1,
                                                  const float* __restrict__ W2,
                                                  const float* __restrict__ W3,
                                                  u16* __restrict__ w1t,
                                                  u16* __restrict__ w2t,
                                                  u16* __restrict__ w3t,
                                                  unsigned* __restrict__ flags) {
  int id = blockIdx.x * 256 + threadIdx.x;
  if (id < 8192) flags[id] = 0u;  // sync flags for lstm (re-zeroed every launch)
  if (id < 131072) { int n = id >> 9, k = id & 511; w1t[id] = f2h(W1[k * 256 + n]); return; }
  id -= 131072;
  if (id < 65536) { int n = id >> 8, k = id & 255; w2t[id] = f2h(W2[k * 256 + n]); return; }
  id -= 65536;
  if (id < 32768) { int n = id >> 8, k = id & 255; w3t[id] = f2h(W3[k * 128 + n]); }
}

// ---- bidirectional LSTM v9: v8 minus LDS staging (direct-global A-frags) ---
// 256 blocks = q(4 gate-slices) x dir(2) x grp(32 batch-groups of 16 rows),
// bid = q*64 + dir*32 + grp. Block owns gate-cols tau_g in [16q,16q+16):
// Wh slice (128 KB) LDS-resident, Wi slice in 32 pinned VGPR/wave.
// v9 change (v8 had 29.4M LDS bank conflicts from the 8-way-conflicted
// af staging reads): A-fragments are loaded DIRECTLY from global --
//   x frags from x0 (f32->f16 in regs, issued BEFORE the flag spin: hidden),
//   h frags from x1 (f16 bits identical to v8's LDS path; L2-hot 64B segs).
// This deletes both staging phases and 2 of 4 barriers. Spin is all-thread
// (one coalesced poll per wave, s_sleep(2)). Numerics bit-identical to v8.
__global__ __launch_bounds__(512, 2) void lstm_kernel(
    const float* __restrict__ x0, const u16* __restrict__ wpack,
    const float* __restrict__ bi_f, const float* __restrict__ bh_f,
    const float* __restrict__ bi_r, const float* __restrict__ bh_r,
    u16* __restrict__ x1, unsigned* __restrict__ flags) {
  __shared__ __align__(16) u16 lwh[16][8][64][8];  // 128 KB Wh kb4..11, 16 taus
  __shared__ __align__(16) float gbuf[16][257];    // gate pre-activations (f32)

  const int tid = threadIdx.x;
  const int lane = tid & 63;
  const int w = tid >> 6;             // wave 0..7
  const int bid = blockIdx.x;
  const int q = bid >> 6;             // gate-slice 0..3
  const int rem = bid & 63;
  const int dir = rem >> 5;
  const int grp = rem & 31;
  const int b0 = grp * 16;
  const u16* wpk = wpack + (size_t)dir * (64 * 12 * 64 * 8);
  const float* bi = dir ? bi_r : bi_f;
  const float* bh = dir ? bh_r : bh_f;
  const int mrow = lane & 15, quad = lane >> 4;
  const int tauL0 = 2 * w;            // this wave's 2 local n-tiles
  unsigned* flg = flags + (size_t)(dir * 32 + grp) * 128;

  // biases for the wave's 2 taus
  float bias2[2];
#pragma unroll
  for (int lt = 0; lt < 2; ++lt) {
    int tau_g = 16 * q + tauL0 + lt;
    int n = (tau_g & 3) * 256 + (tau_g >> 2) * 16 + mrow;
    bias2[lt] = bi[n] + bh[n];
  }

  // Wh kb4..11 for the block's 16 taus -> LDS (8192 frags of 16 B)
#pragma unroll
  for (int r = 0; r < 16; ++r) {
    int d = r * 512 + tid;
    int ltau = d >> 9, lkb = (d >> 6) & 7, ll = d & 63;
    *(i16x8_t*)&lwh[ltau][lkb][ll][0] =
        *(const i16x8_t*)(wpk + (((size_t)(16 * q + ltau) * 12 + 4 + lkb) * 64 + ll) * 8);
  }
  // Wi kb0..3 for the wave's 2 taus -> registers (32 VGPR), pinned
  i16x8_t wir[2][4];
#pragma unroll
  for (int lt = 0; lt < 2; ++lt)
#pragma unroll
    for (int kb = 0; kb < 4; ++kb) {
      wir[lt][kb] =
          *(const i16x8_t*)(wpk + (((size_t)(16 * q + tauL0 + lt) * 12 + kb) * 64 + lane) * 8);
      PIN(wir[lt][kb]);
    }
  __syncthreads();  // lwh ready

  // c-state: thread owns 2 adjacent cells (row = tid>>5, jj = 2*(tid&31)+e)
  const int crow = tid >> 5;
  const int cj0 = (tid & 31) * 2;
  float c0 = 0.f, c1 = 0.f;

  // per-lane global bases for A-fragment loads
  const float* xfrag_base = x0 + (size_t)(b0 + mrow) * 16384 + quad * 8;
  const u16* hfrag_base = x1 + (size_t)(b0 + mrow) * 65536 + dir * 256 + quad * 8;

  for (int t = 0; t < 128; ++t) {
    const int teff = dir ? 127 - t : t;

    // x fragments: direct from x0, f32->f16 in regs (independent of flag)
    i16x8_t afx[4];
    {
      const float* xp = xfrag_base + (size_t)teff * 128;
#pragma unroll
      for (int kb = 0; kb < 4; ++kb) {
        float4 va = *(const float4*)(xp + kb * 32);
        float4 vb = *(const float4*)(xp + kb * 32 + 4);
        i16x8_t v;
        v[0] = (short)f2h(va.x); v[1] = (short)f2h(va.y);
        v[2] = (short)f2h(va.z); v[3] = (short)f2h(va.w);
        v[4] = (short)f2h(vb.x); v[5] = (short)f2h(vb.y);
        v[6] = (short)f2h(vb.z); v[7] = (short)f2h(vb.w);
        afx[kb] = v;
      }
    }

    // wait for all 4 siblings' h_{t-1} (all threads poll one coalesced addr)
    if (t > 0) {
      unsigned iter = 0;
      while (__hip_atomic_load(&flg[t - 1], __ATOMIC_RELAXED, __HIP_MEMORY_SCOPE_AGENT) < 4u) {
        __builtin_amdgcn_s_sleep(2);
        if (++iter > (8u << 20)) break;  // fail-safe: deadlock -> wrong answer, not hang
      }
      (void)__hip_atomic_load(&flg[t - 1], __ATOMIC_ACQUIRE, __HIP_MEMORY_SCOPE_AGENT);
    }

    // h fragments: direct from x1 (8 independent L2-hot 16B loads/lane)
    i16x8_t afh[8];
    if (t > 0) {
      const u16* hp = hfrag_base + (size_t)(t - 1) * 512;
#pragma unroll
      for (int kb = 0; kb < 8; ++kb)
        afh[kb] = *(const i16x8_t*)(hp + kb * 32);
    } else {
#pragma unroll
      for (int kb = 0; kb < 8; ++kb) afh[kb] = (i16x8_t){0, 0, 0, 0, 0, 0, 0, 0};
    }

    // MFMA phase: 24 MFMA/wave, operands in regs/LDS
#pragma unroll
    for (int lt = 0; lt < 2; ++lt) {
      float bv = bias2[lt];
      f32x4_t a = {bv, bv, bv, bv};
      a = mfma16h(afx[0], wir[lt][0], a);
      a = mfma16h(afx[1], wir[lt][1], a);
      a = mfma16h(afx[2], wir[lt][2], a);
      a = mfma16h(afx[3], wir[lt][3], a);
#pragma unroll
      for (int kb = 0; kb < 8; ++kb)
        a = mfma16h(afh[kb], *(const i16x8_t*)&lwh[tauL0 + lt][kb][lane][0], a);
      int col = (tauL0 + lt) * 16 + mrow;
#pragma unroll
      for (int r = 0; r < 4; ++r) gbuf[quad * 4 + r][col] = a[r];
    }
    __syncthreads();  // (1) gbuf ready

    // gate phase: 2 cells/thread; col(g) = jb_l*64 + g*16 + mr
    {
      float hv[2];
#pragma unroll
      for (int e = 0; e < 2; ++e) {
        int jj = cj0 + e;
        int base = (jj >> 4) * 64 + (jj & 15);
        float fg = gbuf[crow][base];
        float ig = gbuf[crow][base + 16];
        float ag = gbuf[crow][base + 32];
        float og = gbuf[crow][base + 48];
        float cc = e ? c1 : c0;
        float cv = sigmoidf_(fg) * cc + sigmoidf_(ig) * tanhf_(ag);
        if (e) c1 = cv; else c0 = cv;
        hv[e] = sigmoidf_(og) * tanhf_(cv);
      }
      unsigned pack = (unsigned)f2h(hv[0]) | ((unsigned)f2h(hv[1]) << 16);
      *(unsigned*)(x1 + ((size_t)((b0 + crow) * 128 + t)) * 512 + dir * 256 + 64 * q + cj0) =
          pack;
    }
    __syncthreads();  // (2) h stores drained (barrier implies vmcnt(0)); gbuf reads done
    if (tid == 0 && t < 127)
      __hip_atomic_fetch_add(&flg[t], 1u, __ATOMIC_RELEASE, __HIP_MEMORY_SCOPE_AGENT);
  }
}

// ---- fused MLP + heads (unchanged — passing) ------------------------------
__global__ __launch_bounds__(512, 1) void mlp_kernel(
    const u16* __restrict__ x1, const u16* __restrict__ w1t,
    const u16* __restrict__ w2t, const u16* __restrict__ w3t,
    const float* __restrict__ b1, const float* __restrict__ b2,
    const float* __restrict__ b3, float* __restrict__ out) {
  __shared__ __align__(16) u16 X2[128][264];
  __shared__ __align__(16) u16 X3[128][264];
  const int tid = threadIdx.x;
  const int lane = tid & 63, wv = tid >> 6;
  const int mrow = lane & 15, quad = lane >> 4;
  const int r0 = blockIdx.x * 128;
  const f32x4_t zero4 = {0.f, 0.f, 0.f, 0.f};

  // stage 1: X2[128][256] = leaky(x1[128,512] @ W1 + b1)
  {
    f32x4_t acc[16];
#pragma unroll
    for (int n = 0; n < 16; ++n) acc[n] = zero4;
    for (int kb = 0; kb < 16; ++kb) {
      int k = kb * 32 + quad * 8;
      i16x8_t a = *(const i16x8_t*)(x1 + (size_t)(r0 + wv * 16 + mrow) * 512 + k);
#pragma unroll
      for (int n = 0; n < 16; ++n) {
        i16x8_t b = *(const i16x8_t*)(w1t + (n * 16 + mrow) * 512 + k);
        acc[n] = mfma16h(a, b, acc[n]);
      }
    }
#pragma unroll
    for (int n = 0; n < 16; ++n)
#pragma unroll
      for (int r = 0; r < 4; ++r) {
        int m = wv * 16 + quad * 4 + r;
        int col = n * 16 + mrow;
        float v = acc[n][r] + b1[col];
        v = v > 0.f ? v : 0.1f * v;
        X2[m][col] = f2h(v);
      }
  }
  __syncthreads();

  // stage 2: X3[128][256] = leaky(X2 @ W2 + b2), K=256
  {
    f32x4_t acc[16];
#pragma unroll
    for (int n = 0; n < 16; ++n) acc[n] = zero4;
#pragma unroll
    for (int kb = 0; kb < 8; ++kb) {
      int k = kb * 32 + quad * 8;
      i16x8_t a = *(const i16x8_t*)&X2[wv * 16 + mrow][k];
#pragma unroll
      for (int n = 0; n < 16; ++n) {
        i16x8_t b = *(const i16x8_t*)(w2t + (n * 16 + mrow) * 256 + k);
        acc[n] = mfma16h(a, b, acc[n]);
      }
    }
#pragma unroll
    for (int n = 0; n < 16; ++n)
#pragma unroll
      for (int r = 0; r < 4; ++r) {
        int m = wv * 16 + quad * 4 + r;
        int col = n * 16 + mrow;
        float v = acc[n][r] + b2[col];
        v = v > 0.f ? v : 0.1f * v;
        X3[m][col] = f2h(v);
      }
  }
  __syncthreads();

  // stage 3: XF[128][128] = X3 @ W3 + b3 (fp32; overlays dead X2)
  float (*XF)[130] = (float (*)[130]) & X2[0][0];
  {
    f32x4_t acc[8];
#pragma unroll
    for (int n = 0; n < 8; ++n) acc[n] = zero4;
#pragma unroll
    for (int kb = 0; kb < 8; ++kb) {
      int k = kb * 32 + quad * 8;
      i16x8_t a = *(const i16x8_t*)&X3[wv * 16 + mrow][k];
#pragma unroll
      for (int n = 0; n < 8; ++n) {
        i16x8_t b = *(const i16x8_t*)(w3t + (n * 16 + mrow) * 256 + k);
        acc[n] = mfma16h(a, b, acc[n]);
      }
    }
#pragma unroll
    for (int n = 0; n < 8; ++n)
#pragma unroll
      for (int r = 0; r < 4; ++r) {
        int m = wv * 16 + quad * 4 + r;
        int col = n * 16 + mrow;
        XF[m][col] = acc[n][r] + b3[col];
      }
  }
  __syncthreads();

  // heads: cols 0:64 sigmoid; softmax over [64,72), [72,88), [88,128)
  if (tid < 128) {
    int row = tid;
    float* xr = XF[row];
    float* op = out + (size_t)(r0 + row) * 128;
    for (int cc = 0; cc < 64; ++cc) op[cc] = sigmoidf_(xr[cc]);
  } else if (tid < 256) {
    int row = tid - 128;
    float* xr = XF[row];
    float* op = out + (size_t)(r0 + row) * 128;
    const int s0s[3] = {64, 72, 88};
    const int s1s[3] = {72, 88, 128};
    for (int s = 0; s < 3; ++s) {
      int s0 = s0s[s], s1 = s1s[s];
      float mx = xr[s0];
      for (int q = s0 + 1; q < s1; ++q) mx = fmaxf(mx, xr[q]);
      float sum = 0.f;
      for (int q = s0; q < s1; ++q) { float e = __expf(xr[q] - mx); xr[q] = e; sum += e; }
      float inv = 1.f / sum;
      for (int q = s0; q < s1; ++q) op[q] = xr[q] * inv;
    }
  }
}

// ---- launch ----------------------------------------------------------------
extern "C" void kernel_launch(void* const* d_in, const int* in_sizes, int n_in,
                              void* d_out, int out_size, void* d_ws, size_t ws_size,
                              hipStream_t stream) {
  const float* x0   = (const float*)d_in[0];
  const float* Wi_f = (const float*)d_in[1];
  const float* bi_f = (const float*)d_in[2];
  const float* Wh_f = (const float*)d_in[3];
  const float* bh_f = (const float*)d_in[4];
  const float* Wi_r = (const float*)d_in[5];
  const float* bi_r = (const float*)d_in[6];
  const float* Wh_r = (const float*)d_in[7];
  const float* bh_r = (const float*)d_in[8];
  const float* W1 = (const float*)d_in[9];
  const float* b1 = (const float*)d_in[10];
  const float* W2 = (const float*)d_in[11];
  const float* b2 = (const float*)d_in[12];
  const float* W3 = (const float*)d_in[13];
  const float* b3 = (const float*)d_in[14];
  float* out = (float*)d_out;

  char* ws = (char*)d_ws;
  u16* w1t   = (u16*)(ws + 0);         // 262144 B
  u16* w2t   = (u16*)(ws + 262144);    // 131072 B
  u16* w3t   = (u16*)(ws + 393216);    // 65536 B
  u16* wpack = (u16*)(ws + 458752);    // 1572864 B
  u16* x1    = (u16*)(ws + 2031616);   // 67108864 B
  unsigned* flags = (unsigned*)(ws + 69140480);  // 32768 B

  hipLaunchKernelGGL(prep_wpack, dim3(3072), dim3(256), 0, stream,
                     Wi_f, Wh_f, Wi_r, Wh_r, wpack);
  hipLaunchKernelGGL(prep_small, dim3(896), dim3(256), 0, stream,
                     W1, W2, W3, w1t, w2t, w3t, flags);
  {
    void* params[8];
    params[0] = (void*)&x0;
    params[1] = (void*)&wpack;
    params[2] = (void*)&bi_f;
    params[3] = (void*)&bh_f;
    params[4] = (void*)&bi_r;
    params[5] = (void*)&bh_r;
    params[6] = (void*)&x1;
    params[7] = (void*)&flags;
    hipLaunchCooperativeKernel((const void*)lstm_kernel, dim3(256), dim3(512),
                               params, 0, stream);
  }
  hipLaunchKernelGGL(mlp_kernel, dim3(512), dim3(512), 0, stream,
                     x1, w1t, w2t, w3t, b1, b2, b3, out);
}

// Round 7
// 1116.714 us; speedup vs baseline: 2.4011x; 2.4011x over previous
//
#include <hip/hip_runtime.h>

typedef unsigned short u16;
typedef _Float16 f16x8_t __attribute__((ext_vector_type(8)));
typedef short    i16x8_t __attribute__((ext_vector_type(8)));
typedef short    i16x4_t __attribute__((ext_vector_type(4)));
typedef float    f32x4_t __attribute__((ext_vector_type(4)));

// force a loaded value to stay materialized in VGPRs (no remat/sinking)
#define PIN(x) asm volatile("" : "+v"(x))

// ---- helpers ---------------------------------------------------------------
static __device__ __forceinline__ u16 f2h(float f) {
  _Float16 h = (_Float16)f;  // RNE
  return __builtin_bit_cast(u16, h);
}
static __device__ __forceinline__ f32x4_t mfma16h(i16x8_t a, i16x8_t b, f32x4_t c) {
  return __builtin_amdgcn_mfma_f32_16x16x32_f16(
      __builtin_bit_cast(f16x8_t, a), __builtin_bit_cast(f16x8_t, b), c, 0, 0, 0);
}
static __device__ __forceinline__ float sigmoidf_(float x) { return 1.f / (1.f + __expf(-x)); }
static __device__ __forceinline__ float tanhf_(float x) { return 1.f - 2.f / (__expf(2.f * x) + 1.f); }

// ---- prep: LSTM weights pre-swizzled into MFMA fragment order --------------
// wpack[dir][tau][kb][lane][8]: tau = jb*4+g (jb = j-block, g = gate),
// kb in [0,12), lane = quad*16+mrow. Element e: n = g*256+jb*16+mrow,
// k = kb*32+quad*8+e; value = k<128 ? Wi[k][n] : Wh[k-128][n].
__global__ __launch_bounds__(256) void prep_wpack(const float* __restrict__ Wi_f,
                                                  const float* __restrict__ Wh_f,
                                                  const float* __restrict__ Wi_r,
                                                  const float* __restrict__ Wh_r,
                                                  u16* __restrict__ wpack) {
  int id = blockIdx.x * 256 + threadIdx.x;
  if (id >= 786432) return;  // 2*64*12*64*8
  int e = id & 7, r = id >> 3;
  int lane = r & 63; r >>= 6;
  int kb = r % 12; r /= 12;
  int tau = r & 63, dir = r >> 6;
  int mrow = lane & 15, quad = lane >> 4;
  int jb = tau >> 2, g = tau & 3;
  int n = g * 256 + jb * 16 + mrow;
  int k = kb * 32 + quad * 8 + e;
  const float* Wi = dir ? Wi_r : Wi_f;
  const float* Wh = dir ? Wh_r : Wh_f;
  float v = (k < 128) ? Wi[k * 1024 + n] : Wh[(k - 128) * 1024 + n];
  wpack[id] = f2h(v);
}

// ---- prep: MLP W^T in f16 + flag zeroing ----------------------------------
__global__ __launch_bounds__(256) void prep_small(const float* __restrict__ W1,
                                                  const float* __restrict__ W2,
                                                  const float* __restrict__ W3,
                                                  u16* __restrict__ w1t,
                                                  u16* __restrict__ w2t,
                                                  u16* __restrict__ w3t,
                                                  unsigned* __restrict__ flags) {
  int id = blockIdx.x * 256 + threadIdx.x;
  if (id < 8192) flags[id] = 0u;  // sync flags for lstm (re-zeroed every launch)
  if (id < 131072) { int n = id >> 9, k = id & 511; w1t[id] = f2h(W1[k * 256 + n]); return; }
  id -= 131072;
  if (id < 65536) { int n = id >> 8, k = id & 255; w2t[id] = f2h(W2[k * 256 + n]); return; }
  id -= 65536;
  if (id < 32768) { int n = id >> 8, k = id & 255; w3t[id] = f2h(W3[k * 128 + n]); }
}

// ---- bidirectional LSTM v10: v8 sync/staging + swizzled LDS + Wi-overlap ---
// 256 blocks = q(4 gate-slices) x dir(2) x grp(32 batch-groups of 16 rows),
// bid = q*64 + dir*32 + grp. Block owns gate-cols tau_g in [16q,16q+16):
// Wh slice (128 KB) LDS-resident, Wi slice in 32 pinned VGPR/wave.
// Fixes vs v8/v9:
//  - ah staging XOR-swizzled (u16 idx ^= (row&7)<<3): the 8 ds_read_b128
//    h-frag reads are bank-conflict-free (v8: 29.4M conflict cycles).
//  - x frags loaded direct from x0 to regs and the 8 Wi MFMAs computed
//    BEFORE the flag spin -> x-projection hides under the inter-block wait.
//  - tid0-only spin (v9's all-thread spin melted the fabric), s_sleep(4).
//  - h staged coalesced from x1 (v9's direct h-frag loads were 16-segment
//    scatters in the post-flag critical path).
// Numerics: identical MFMA order (bias -> Wi kb0..3 -> Wh kb0..7) and f16
// conversion points as v8/v9.
__global__ __launch_bounds__(512, 2) void lstm_kernel(
    const float* __restrict__ x0, const u16* __restrict__ wpack,
    const float* __restrict__ bi_f, const float* __restrict__ bh_f,
    const float* __restrict__ bi_r, const float* __restrict__ bh_r,
    u16* __restrict__ x1, unsigned* __restrict__ flags) {
  __shared__ __align__(16) u16 lwh[16][8][64][8];  // 128 KB Wh kb4..11, 16 taus
  __shared__ __align__(16) u16 ah[16][256];        // 8 KB h panel, XOR-swizzled
  __shared__ __align__(16) float gbuf[16][260];    // gate pre-activations (f32)

  const int tid = threadIdx.x;
  const int lane = tid & 63;
  const int w = tid >> 6;             // wave 0..7
  const int bid = blockIdx.x;
  const int q = bid >> 6;             // gate-slice 0..3
  const int rem = bid & 63;
  const int dir = rem >> 5;
  const int grp = rem & 31;
  const int b0 = grp * 16;
  const u16* wpk = wpack + (size_t)dir * (64 * 12 * 64 * 8);
  const float* bi = dir ? bi_r : bi_f;
  const float* bh = dir ? bh_r : bh_f;
  const int mrow = lane & 15, quad = lane >> 4;
  const int tauL0 = 2 * w;            // this wave's 2 local n-tiles
  unsigned* flg = flags + (size_t)(dir * 32 + grp) * 128;

  // biases for the wave's 2 taus
  float bias2[2];
#pragma unroll
  for (int lt = 0; lt < 2; ++lt) {
    int tau_g = 16 * q + tauL0 + lt;
    int n = (tau_g & 3) * 256 + (tau_g >> 2) * 16 + mrow;
    bias2[lt] = bi[n] + bh[n];
  }

  // Wh kb4..11 for the block's 16 taus -> LDS (8192 frags of 16 B)
#pragma unroll
  for (int r = 0; r < 16; ++r) {
    int d = r * 512 + tid;
    int ltau = d >> 9, lkb = (d >> 6) & 7, ll = d & 63;
    *(i16x8_t*)&lwh[ltau][lkb][ll][0] =
        *(const i16x8_t*)(wpk + (((size_t)(16 * q + ltau) * 12 + 4 + lkb) * 64 + ll) * 8);
  }
  // Wi kb0..3 for the wave's 2 taus -> registers (32 VGPR), pinned
  i16x8_t wir[2][4];
#pragma unroll
  for (int lt = 0; lt < 2; ++lt)
#pragma unroll
    for (int kb = 0; kb < 4; ++kb) {
      wir[lt][kb] =
          *(const i16x8_t*)(wpk + (((size_t)(16 * q + tauL0 + lt) * 12 + kb) * 64 + lane) * 8);
      PIN(wir[lt][kb]);
    }
  __syncthreads();  // lwh ready

  // c-state: thread owns 2 adjacent cells (row = tid>>5, jj = 2*(tid&31)+e)
  const int crow = tid >> 5;
  const int cj0 = (tid & 31) * 2;
  float c0 = 0.f, c1 = 0.f;

  // per-lane global base for x-fragment loads (direct, pre-spin)
  const float* xfrag_base = x0 + (size_t)(b0 + mrow) * 16384 + quad * 8;
  // h staging: 16B/thread, coalesced rows; LDS dst is XOR-swizzled
  const int fm = tid >> 5, fj = (tid & 31) * 8;
  const u16* hstage_src = x1 + (size_t)(b0 + fm) * 65536 + dir * 256 + fj;
  u16* ah_dst = &ah[fm][fj ^ ((fm & 7) << 3)];

  for (int t = 0; t < 128; ++t) {
    const int teff = dir ? 127 - t : t;

    // x fragments: direct from x0, f32->f16 in regs (flag-independent)
    i16x8_t afx[4];
    {
      const float* xp = xfrag_base + (size_t)teff * 128;
#pragma unroll
      for (int kb = 0; kb < 4; ++kb) {
        float4 va = *(const float4*)(xp + kb * 32);
        float4 vb = *(const float4*)(xp + kb * 32 + 4);
        i16x8_t v;
        v[0] = (short)f2h(va.x); v[1] = (short)f2h(va.y);
        v[2] = (short)f2h(va.z); v[3] = (short)f2h(va.w);
        v[4] = (short)f2h(vb.x); v[5] = (short)f2h(vb.y);
        v[6] = (short)f2h(vb.z); v[7] = (short)f2h(vb.w);
        afx[kb] = v;
      }
    }
    // x-projection MFMAs BEFORE the spin (overlap with producers finishing)
    f32x4_t acc[2];
#pragma unroll
    for (int lt = 0; lt < 2; ++lt) {
      float bv = bias2[lt];
      f32x4_t a = {bv, bv, bv, bv};
      a = mfma16h(afx[0], wir[lt][0], a);
      a = mfma16h(afx[1], wir[lt][1], a);
      a = mfma16h(afx[2], wir[lt][2], a);
      a = mfma16h(afx[3], wir[lt][3], a);
      acc[lt] = a;
    }

    // wait for all 4 siblings' h_{t-1}: tid0 polls, block-wide via barrier
    if (t > 0 && tid == 0) {
      unsigned iter = 0;
      while (__hip_atomic_load(&flg[t - 1], __ATOMIC_RELAXED, __HIP_MEMORY_SCOPE_AGENT) < 4u) {
        __builtin_amdgcn_s_sleep(4);
        if (++iter > (8u << 20)) break;  // fail-safe: deadlock -> wrong answer, not hang
      }
      (void)__hip_atomic_load(&flg[t - 1], __ATOMIC_ACQUIRE, __HIP_MEMORY_SCOPE_AGENT);
    }
    __syncthreads();  // (1) flag seen by all; prev-step ah/gbuf reads done

    if (t > 0) {  // stage h_{t-1} (all 4 slices) coalesced -> swizzled LDS
      *(i16x8_t*)ah_dst = *(const i16x8_t*)(hstage_src + (size_t)(t - 1) * 512);
    }
    __syncthreads();  // (2) ah ready

    if (t > 0) {  // h-part MFMAs: conflict-free swizzled ds_read_b128
      i16x8_t afh[8];
#pragma unroll
      for (int kb = 0; kb < 8; ++kb)
        afh[kb] = *(const i16x8_t*)&ah[mrow][(kb * 32 + quad * 8) ^ ((mrow & 7) << 3)];
#pragma unroll
      for (int lt = 0; lt < 2; ++lt) {
#pragma unroll
        for (int kb = 0; kb < 8; ++kb)
          acc[lt] = mfma16h(afh[kb], *(const i16x8_t*)&lwh[tauL0 + lt][kb][lane][0], acc[lt]);
      }
    }
    // write gate pre-activations
#pragma unroll
    for (int lt = 0; lt < 2; ++lt) {
      int col = (tauL0 + lt) * 16 + mrow;
#pragma unroll
      for (int r = 0; r < 4; ++r) gbuf[quad * 4 + r][col] = acc[lt][r];
    }
    __syncthreads();  // (3) gbuf ready

    // gate phase: 2 cells/thread; col(g) = jb_l*64 + g*16 + mr
    {
      float hv[2];
#pragma unroll
      for (int e = 0; e < 2; ++e) {
        int jj = cj0 + e;
        int base = (jj >> 4) * 64 + (jj & 15);
        float fg = gbuf[crow][base];
        float ig = gbuf[crow][base + 16];
        float ag = gbuf[crow][base + 32];
        float og = gbuf[crow][base + 48];
        float cc = e ? c1 : c0;
        float cv = sigmoidf_(fg) * cc + sigmoidf_(ig) * tanhf_(ag);
        if (e) c1 = cv; else c0 = cv;
        hv[e] = sigmoidf_(og) * tanhf_(cv);
      }
      unsigned pack = (unsigned)f2h(hv[0]) | ((unsigned)f2h(hv[1]) << 16);
      *(unsigned*)(x1 + ((size_t)((b0 + crow) * 128 + t)) * 512 + dir * 256 + 64 * q + cj0) =
          pack;
    }
    __syncthreads();  // (4) h stores drained (barrier implies vmcnt(0))
    if (tid == 0 && t < 127)
      __hip_atomic_fetch_add(&flg[t], 1u, __ATOMIC_RELEASE, __HIP_MEMORY_SCOPE_AGENT);
  }
}

// ---- fused MLP + heads (unchanged — passing) ------------------------------
__global__ __launch_bounds__(512, 1) void mlp_kernel(
    const u16* __restrict__ x1, const u16* __restrict__ w1t,
    const u16* __restrict__ w2t, const u16* __restrict__ w3t,
    const float* __restrict__ b1, const float* __restrict__ b2,
    const float* __restrict__ b3, float* __restrict__ out) {
  __shared__ __align__(16) u16 X2[128][264];
  __shared__ __align__(16) u16 X3[128][264];
  const int tid = threadIdx.x;
  const int lane = tid & 63, wv = tid >> 6;
  const int mrow = lane & 15, quad = lane >> 4;
  const int r0 = blockIdx.x * 128;
  const f32x4_t zero4 = {0.f, 0.f, 0.f, 0.f};

  // stage 1: X2[128][256] = leaky(x1[128,512] @ W1 + b1)
  {
    f32x4_t acc[16];
#pragma unroll
    for (int n = 0; n < 16; ++n) acc[n] = zero4;
    for (int kb = 0; kb < 16; ++kb) {
      int k = kb * 32 + quad * 8;
      i16x8_t a = *(const i16x8_t*)(x1 + (size_t)(r0 + wv * 16 + mrow) * 512 + k);
#pragma unroll
      for (int n = 0; n < 16; ++n) {
        i16x8_t b = *(const i16x8_t*)(w1t + (n * 16 + mrow) * 512 + k);
        acc[n] = mfma16h(a, b, acc[n]);
      }
    }
#pragma unroll
    for (int n = 0; n < 16; ++n)
#pragma unroll
      for (int r = 0; r < 4; ++r) {
        int m = wv * 16 + quad * 4 + r;
        int col = n * 16 + mrow;
        float v = acc[n][r] + b1[col];
        v = v > 0.f ? v : 0.1f * v;
        X2[m][col] = f2h(v);
      }
  }
  __syncthreads();

  // stage 2: X3[128][256] = leaky(X2 @ W2 + b2), K=256
  {
    f32x4_t acc[16];
#pragma unroll
    for (int n = 0; n < 16; ++n) acc[n] = zero4;
#pragma unroll
    for (int kb = 0; kb < 8; ++kb) {
      int k = kb * 32 + quad * 8;
      i16x8_t a = *(const i16x8_t*)&X2[wv * 16 + mrow][k];
#pragma unroll
      for (int n = 0; n < 16; ++n) {
        i16x8_t b = *(const i16x8_t*)(w2t + (n * 16 + mrow) * 256 + k);
        acc[n] = mfma16h(a, b, acc[n]);
      }
    }
#pragma unroll
    for (int n = 0; n < 16; ++n)
#pragma unroll
      for (int r = 0; r < 4; ++r) {
        int m = wv * 16 + quad * 4 + r;
        int col = n * 16 + mrow;
        float v = acc[n][r] + b2[col];
        v = v > 0.f ? v : 0.1f * v;
        X3[m][col] = f2h(v);
      }
  }
  __syncthreads();

  // stage 3: XF[128][128] = X3 @ W3 + b3 (fp32; overlays dead X2)
  float (*XF)[130] = (float (*)[130]) & X2[0][0];
  {
    f32x4_t acc[8];
#pragma unroll
    for (int n = 0; n < 8; ++n) acc[n] = zero4;
#pragma unroll
    for (int kb = 0; kb < 8; ++kb) {
      int k = kb * 32 + quad * 8;
      i16x8_t a = *(const i16x8_t*)&X3[wv * 16 + mrow][k];
#pragma unroll
      for (int n = 0; n < 8; ++n) {
        i16x8_t b = *(const i16x8_t*)(w3t + (n * 16 + mrow) * 256 + k);
        acc[n] = mfma16h(a, b, acc[n]);
      }
    }
#pragma unroll
    for (int n = 0; n < 8; ++n)
#pragma unroll
      for (int r = 0; r < 4; ++r) {
        int m = wv * 16 + quad * 4 + r;
        int col = n * 16 + mrow;
        XF[m][col] = acc[n][r] + b3[col];
      }
  }
  __syncthreads();

  // heads: cols 0:64 sigmoid; softmax over [64,72), [72,88), [88,128)
  if (tid < 128) {
    int row = tid;
    float* xr = XF[row];
    float* op = out + (size_t)(r0 + row) * 128;
    for (int cc = 0; cc < 64; ++cc) op[cc] = sigmoidf_(xr[cc]);
  } else if (tid < 256) {
    int row = tid - 128;
    float* xr = XF[row];
    float* op = out + (size_t)(r0 + row) * 128;
    const int s0s[3] = {64, 72, 88};
    const int s1s[3] = {72, 88, 128};
    for (int s = 0; s < 3; ++s) {
      int s0 = s0s[s], s1 = s1s[s];
      float mx = xr[s0];
      for (int q = s0 + 1; q < s1; ++q) mx = fmaxf(mx, xr[q]);
      float sum = 0.f;
      for (int q = s0; q < s1; ++q) { float e = __expf(xr[q] - mx); xr[q] = e; sum += e; }
      float inv = 1.f / sum;
      for (int q = s0; q < s1; ++q) op[q] = xr[q] * inv;
    }
  }
}

// ---- launch ----------------------------------------------------------------
extern "C" void kernel_launch(void* const* d_in, const int* in_sizes, int n_in,
                              void* d_out, int out_size, void* d_ws, size_t ws_size,
                              hipStream_t stream) {
  const float* x0   = (const float*)d_in[0];
  const float* Wi_f = (const float*)d_in[1];
  const float* bi_f = (const float*)d_in[2];
  const float* Wh_f = (const float*)d_in[3];
  const float* bh_f = (const float*)d_in[4];
  const float* Wi_r = (const float*)d_in[5];
  const float* bi_r = (const float*)d_in[6];
  const float* Wh_r = (const float*)d_in[7];
  const float* bh_r = (const float*)d_in[8];
  const float* W1 = (const float*)d_in[9];
  const float* b1 = (const float*)d_in[10];
  const float* W2 = (const float*)d_in[11];
  const float* b2 = (const float*)d_in[12];
  const float* W3 = (const float*)d_in[13];
  const float* b3 = (const float*)d_in[14];
  float* out = (float*)d_out;

  char* ws = (char*)d_ws;
  u16* w1t   = (u16*)(ws + 0);         // 262144 B
  u16* w2t   = (u16*)(ws + 262144);    // 131072 B
  u16* w3t   = (u16*)(ws + 393216);    // 65536 B
  u16* wpack = (u16*)(ws + 458752);    // 1572864 B
  u16* x1    = (u16*)(ws + 2031616);   // 67108864 B
  unsigned* flags = (unsigned*)(ws + 69140480);  // 32768 B

  hipLaunchKernelGGL(prep_wpack, dim3(3072), dim3(256), 0, stream,
                     Wi_f, Wh_f, Wi_r, Wh_r, wpack);
  hipLaunchKernelGGL(prep_small, dim3(896), dim3(256), 0, stream,
                     W1, W2, W3, w1t, w2t, w3t, flags);
  {
    void* params[8];
    params[0] = (void*)&x0;
    params[1] = (void*)&wpack;
    params[2] = (void*)&bi_f;
    params[3] = (void*)&bh_f;
    params[4] = (void*)&bi_r;
    params[5] = (void*)&bh_r;
    params[6] = (void*)&x1;
    params[7] = (void*)&flags;
    hipLaunchCooperativeKernel((const void*)lstm_kernel, dim3(256), dim3(512),
                               params, 0, stream);
  }
  hipLaunchKernelGGL(mlp_kernel, dim3(512), dim3(512), 0, stream,
                     x1, w1t, w2t, w3t, b1, b2, b3, out);
}

// Round 8
// 762.439 us; speedup vs baseline: 3.5168x; 1.4647x over previous
//
#include <hip/hip_runtime.h>

typedef unsigned short u16;
typedef unsigned long long u64;
typedef _Float16 f16x8_t __attribute__((ext_vector_type(8)));
typedef short    i16x8_t __attribute__((ext_vector_type(8)));
typedef short    i16x4_t __attribute__((ext_vector_type(4)));
typedef float    f32x4_t __attribute__((ext_vector_type(4)));

// force a loaded value to stay materialized in VGPRs (no remat/sinking)
#define PIN(x) asm volatile("" : "+v"(x))

// ---- helpers ---------------------------------------------------------------
static __device__ __forceinline__ u16 f2h(float f) {
  _Float16 h = (_Float16)f;  // RNE
  return __builtin_bit_cast(u16, h);
}
static __device__ __forceinline__ f32x4_t mfma16h(i16x8_t a, i16x8_t b, f32x4_t c) {
  return __builtin_amdgcn_mfma_f32_16x16x32_f16(
      __builtin_bit_cast(f16x8_t, a), __builtin_bit_cast(f16x8_t, b), c, 0, 0, 0);
}
static __device__ __forceinline__ float sigmoidf_(float x) { return 1.f / (1.f + __expf(-x)); }
static __device__ __forceinline__ float tanhf_(float x) { return 1.f - 2.f / (__expf(2.f * x) + 1.f); }

// ---- prep: LSTM weights pre-swizzled into MFMA fragment order --------------
// wpack[dir][tau][kb][lane][8]: tau = jb*4+g (jb = j-block, g = gate),
// kb in [0,12), lane = quad*16+mrow. Element e: n = g*256+jb*16+mrow,
// k = kb*32+quad*8+e; value = k<128 ? Wi[k][n] : Wh[k-128][n].
__global__ __launch_bounds__(256) void prep_wpack(const float* __restrict__ Wi_f,
                                                  const float* __restrict__ Wh_f,
                                                  const float* __restrict__ Wi_r,
                                                  const float* __restrict__ Wh_r,
                                                  u16* __restrict__ wpack) {
  int id = blockIdx.x * 256 + threadIdx.x;
  if (id >= 786432) return;  // 2*64*12*64*8
  int e = id & 7, r = id >> 3;
  int lane = r & 63; r >>= 6;
  int kb = r % 12; r /= 12;
  int tau = r & 63, dir = r >> 6;
  int mrow = lane & 15, quad = lane >> 4;
  int jb = tau >> 2, g = tau & 3;
  int n = g * 256 + jb * 16 + mrow;
  int k = kb * 32 + quad * 8 + e;
  const float* Wi = dir ? Wi_r : Wi_f;
  const float* Wh = dir ? Wh_r : Wh_f;
  float v = (k < 128) ? Wi[k * 1024 + n] : Wh[(k - 128) * 1024 + n];
  wpack[id] = f2h(v);
}

// ---- prep: MLP W^T in f16 + flag zeroing ----------------------------------
__global__ __launch_bounds__(256) void prep_small(const float* __restrict__ W1,
                                                  const float* __restrict__ W2,
                                                  const float* __restrict__ W3,
                                                  u16* __restrict__ w1t,
                                                  u16* __restrict__ w2t,
                                                  u16* __restrict__ w3t,
                                                  unsigned* __restrict__ flags) {
  int id = blockIdx.x * 256 + threadIdx.x;
  if (id < 8192)  // zero sync flags through LLC (lstm polls them fence-free)
    __hip_atomic_store(&flags[id], 0u, __ATOMIC_RELAXED, __HIP_MEMORY_SCOPE_AGENT);
  if (id < 131072) { int n = id >> 9, k = id & 511; w1t[id] = f2h(W1[k * 256 + n]); return; }
  id -= 131072;
  if (id < 65536) { int n = id >> 8, k = id & 255; w2t[id] = f2h(W2[k * 256 + n]); return; }
  id -= 65536;
  if (id < 32768) { int n = id >> 8, k = id & 255; w3t[id] = f2h(W3[k * 128 + n]); }
}

// ---- bidirectional LSTM v11: v10 minus agent fences (LLC-coherent exchange)-
// 256 blocks = q(4 gate-slices) x dir(2) x grp(32 batch-groups of 16 rows).
// Block owns gate-cols tau_g in [16q,16q+16): Wh slice (128 KB) LDS-resident,
// Wi slice in 32 pinned VGPR/wave. v10's remaining cost was the per-step
// agent release/acquire: buffer_wbl2 + buffer_inv per block per step (32 L2
// walks/XCD/step each way). v11 exchanges h through the Infinity Cache with
// RELAXED agent atomics only (atomics execute at the coherence point, sc1,
// no cache maintenance):
//   producer: atomic-store h (4B, write-through) -> __syncthreads (drains
//             vmcnt(0), so data is at LLC) -> RELAXED flag fetch_add;
//   consumer: tid0 RELAXED-polls flag -> __syncthreads (no hoisting past a
//             barrier) -> stage h via 2x8B RELAXED atomic loads (LLC-direct).
// LLC serializes data-before-flag -> ordering holds with zero fences.
// Numerics bit-identical to v8/v10 (same MFMA order, same f16 points).
__global__ __launch_bounds__(512, 2) void lstm_kernel(
    const float* __restrict__ x0, const u16* __restrict__ wpack,
    const float* __restrict__ bi_f, const float* __restrict__ bh_f,
    const float* __restrict__ bi_r, const float* __restrict__ bh_r,
    u16* __restrict__ x1, unsigned* __restrict__ flags) {
  __shared__ __align__(16) u16 lwh[16][8][64][8];  // 128 KB Wh kb4..11, 16 taus
  __shared__ __align__(16) u16 ah[16][256];        // 8 KB h panel, XOR-swizzled
  __shared__ __align__(16) float gbuf[16][260];    // gate pre-activations (f32)

  const int tid = threadIdx.x;
  const int lane = tid & 63;
  const int w = tid >> 6;             // wave 0..7
  const int bid = blockIdx.x;
  const int q = bid >> 6;             // gate-slice 0..3
  const int rem = bid & 63;
  const int dir = rem >> 5;
  const int grp = rem & 31;
  const int b0 = grp * 16;
  const u16* wpk = wpack + (size_t)dir * (64 * 12 * 64 * 8);
  const float* bi = dir ? bi_r : bi_f;
  const float* bh = dir ? bh_r : bh_f;
  const int mrow = lane & 15, quad = lane >> 4;
  const int tauL0 = 2 * w;            // this wave's 2 local n-tiles
  unsigned* flg = flags + (size_t)(dir * 32 + grp) * 128;

  // biases for the wave's 2 taus
  float bias2[2];
#pragma unroll
  for (int lt = 0; lt < 2; ++lt) {
    int tau_g = 16 * q + tauL0 + lt;
    int n = (tau_g & 3) * 256 + (tau_g >> 2) * 16 + mrow;
    bias2[lt] = bi[n] + bh[n];
  }

  // Wh kb4..11 for the block's 16 taus -> LDS (8192 frags of 16 B)
#pragma unroll
  for (int r = 0; r < 16; ++r) {
    int d = r * 512 + tid;
    int ltau = d >> 9, lkb = (d >> 6) & 7, ll = d & 63;
    *(i16x8_t*)&lwh[ltau][lkb][ll][0] =
        *(const i16x8_t*)(wpk + (((size_t)(16 * q + ltau) * 12 + 4 + lkb) * 64 + ll) * 8);
  }
  // Wi kb0..3 for the wave's 2 taus -> registers (32 VGPR), pinned
  i16x8_t wir[2][4];
#pragma unroll
  for (int lt = 0; lt < 2; ++lt)
#pragma unroll
    for (int kb = 0; kb < 4; ++kb) {
      wir[lt][kb] =
          *(const i16x8_t*)(wpk + (((size_t)(16 * q + tauL0 + lt) * 12 + kb) * 64 + lane) * 8);
      PIN(wir[lt][kb]);
    }
  __syncthreads();  // lwh ready

  // c-state: thread owns 2 adjacent cells (row = tid>>5, jj = 2*(tid&31)+e)
  const int crow = tid >> 5;
  const int cj0 = (tid & 31) * 2;
  float c0 = 0.f, c1 = 0.f;

  // per-lane global base for x-fragment loads (direct, pre-spin)
  const float* xfrag_base = x0 + (size_t)(b0 + mrow) * 16384 + quad * 8;
  // h staging: 16B/thread, coalesced rows; LDS dst is XOR-swizzled
  const int fm = tid >> 5, fj = (tid & 31) * 8;
  const u16* hstage_src = x1 + (size_t)(b0 + fm) * 65536 + dir * 256 + fj;
  u16* ah_dst = &ah[fm][fj ^ ((fm & 7) << 3)];

  for (int t = 0; t < 128; ++t) {
    const int teff = dir ? 127 - t : t;

    // x fragments: direct from x0 (L2-resident now -- no more buffer_inv)
    i16x8_t afx[4];
    {
      const float* xp = xfrag_base + (size_t)teff * 128;
#pragma unroll
      for (int kb = 0; kb < 4; ++kb) {
        float4 va = *(const float4*)(xp + kb * 32);
        float4 vb = *(const float4*)(xp + kb * 32 + 4);
        i16x8_t v;
        v[0] = (short)f2h(va.x); v[1] = (short)f2h(va.y);
        v[2] = (short)f2h(va.z); v[3] = (short)f2h(va.w);
        v[4] = (short)f2h(vb.x); v[5] = (short)f2h(vb.y);
        v[6] = (short)f2h(vb.z); v[7] = (short)f2h(vb.w);
        afx[kb] = v;
      }
    }
    // x-projection MFMAs BEFORE the spin (overlap with producers finishing)
    f32x4_t acc[2];
#pragma unroll
    for (int lt = 0; lt < 2; ++lt) {
      float bv = bias2[lt];
      f32x4_t a = {bv, bv, bv, bv};
      a = mfma16h(afx[0], wir[lt][0], a);
      a = mfma16h(afx[1], wir[lt][1], a);
      a = mfma16h(afx[2], wir[lt][2], a);
      a = mfma16h(afx[3], wir[lt][3], a);
      acc[lt] = a;
    }

    // wait for all 4 siblings' h_{t-1}: tid0 RELAXED-polls the LLC flag
    if (t > 0 && tid == 0) {
      unsigned iter = 0;
      while (__hip_atomic_load(&flg[t - 1], __ATOMIC_RELAXED, __HIP_MEMORY_SCOPE_AGENT) < 4u) {
        __builtin_amdgcn_s_sleep(4);
        if (++iter > (8u << 20)) break;  // fail-safe: deadlock -> wrong answer, not hang
      }
    }
    __syncthreads();  // (1) flag seen by all; prev-step ah/gbuf reads done

    if (t > 0) {  // stage h_{t-1} coalesced from LLC (2x8B relaxed atomics)
      const u64* hsrc = (const u64*)(hstage_src + (size_t)(t - 1) * 512);
      u64 h0 = __hip_atomic_load(hsrc, __ATOMIC_RELAXED, __HIP_MEMORY_SCOPE_AGENT);
      u64 h1 = __hip_atomic_load(hsrc + 1, __ATOMIC_RELAXED, __HIP_MEMORY_SCOPE_AGENT);
      ((u64*)ah_dst)[0] = h0;
      ((u64*)ah_dst)[1] = h1;
    }
    __syncthreads();  // (2) ah ready

    if (t > 0) {  // h-part MFMAs: conflict-free swizzled ds_read_b128
      i16x8_t afh[8];
#pragma unroll
      for (int kb = 0; kb < 8; ++kb)
        afh[kb] = *(const i16x8_t*)&ah[mrow][(kb * 32 + quad * 8) ^ ((mrow & 7) << 3)];
#pragma unroll
      for (int lt = 0; lt < 2; ++lt) {
#pragma unroll
        for (int kb = 0; kb < 8; ++kb)
          acc[lt] = mfma16h(afh[kb], *(const i16x8_t*)&lwh[tauL0 + lt][kb][lane][0], acc[lt]);
      }
    }
    // write gate pre-activations
#pragma unroll
    for (int lt = 0; lt < 2; ++lt) {
      int col = (tauL0 + lt) * 16 + mrow;
#pragma unroll
      for (int r = 0; r < 4; ++r) gbuf[quad * 4 + r][col] = acc[lt][r];
    }
    __syncthreads();  // (3) gbuf ready

    // gate phase: 2 cells/thread; col(g) = jb_l*64 + g*16 + mr
    {
      float hv[2];
#pragma unroll
      for (int e = 0; e < 2; ++e) {
        int jj = cj0 + e;
        int base = (jj >> 4) * 64 + (jj & 15);
        float fg = gbuf[crow][base];
        float ig = gbuf[crow][base + 16];
        float ag = gbuf[crow][base + 32];
        float og = gbuf[crow][base + 48];
        float cc = e ? c1 : c0;
        float cv = sigmoidf_(fg) * cc + sigmoidf_(ig) * tanhf_(ag);
        if (e) c1 = cv; else c0 = cv;
        hv[e] = sigmoidf_(og) * tanhf_(cv);
      }
      unsigned pack = (unsigned)f2h(hv[0]) | ((unsigned)f2h(hv[1]) << 16);
      unsigned* hp = (unsigned*)(x1 + ((size_t)((b0 + crow) * 128 + t)) * 512 +
                                 dir * 256 + 64 * q + cj0);
      // write-through to LLC (no dirty L2 line, no wbl2 ever needed)
      __hip_atomic_store(hp, pack, __ATOMIC_RELAXED, __HIP_MEMORY_SCOPE_AGENT);
    }
    __syncthreads();  // (4) h stores drained to LLC (barrier waits vmcnt(0))
    if (tid == 0 && t < 127)
      __hip_atomic_fetch_add(&flg[t], 1u, __ATOMIC_RELAXED, __HIP_MEMORY_SCOPE_AGENT);
  }
}

// ---- fused MLP + heads (unchanged — passing) ------------------------------
__global__ __launch_bounds__(512, 1) void mlp_kernel(
    const u16* __restrict__ x1, const u16* __restrict__ w1t,
    const u16* __restrict__ w2t, const u16* __restrict__ w3t,
    const float* __restrict__ b1, const float* __restrict__ b2,
    const float* __restrict__ b3, float* __restrict__ out) {
  __shared__ __align__(16) u16 X2[128][264];
  __shared__ __align__(16) u16 X3[128][264];
  const int tid = threadIdx.x;
  const int lane = tid & 63, wv = tid >> 6;
  const int mrow = lane & 15, quad = lane >> 4;
  const int r0 = blockIdx.x * 128;
  const f32x4_t zero4 = {0.f, 0.f, 0.f, 0.f};

  // stage 1: X2[128][256] = leaky(x1[128,512] @ W1 + b1)
  {
    f32x4_t acc[16];
#pragma unroll
    for (int n = 0; n < 16; ++n) acc[n] = zero4;
    for (int kb = 0; kb < 16; ++kb) {
      int k = kb * 32 + quad * 8;
      i16x8_t a = *(const i16x8_t*)(x1 + (size_t)(r0 + wv * 16 + mrow) * 512 + k);
#pragma unroll
      for (int n = 0; n < 16; ++n) {
        i16x8_t b = *(const i16x8_t*)(w1t + (n * 16 + mrow) * 512 + k);
        acc[n] = mfma16h(a, b, acc[n]);
      }
    }
#pragma unroll
    for (int n = 0; n < 16; ++n)
#pragma unroll
      for (int r = 0; r < 4; ++r) {
        int m = wv * 16 + quad * 4 + r;
        int col = n * 16 + mrow;
        float v = acc[n][r] + b1[col];
        v = v > 0.f ? v : 0.1f * v;
        X2[m][col] = f2h(v);
      }
  }
  __syncthreads();

  // stage 2: X3[128][256] = leaky(X2 @ W2 + b2), K=256
  {
    f32x4_t acc[16];
#pragma unroll
    for (int n = 0; n < 16; ++n) acc[n] = zero4;
#pragma unroll
    for (int kb = 0; kb < 8; ++kb) {
      int k = kb * 32 + quad * 8;
      i16x8_t a = *(const i16x8_t*)&X2[wv * 16 + mrow][k];
#pragma unroll
      for (int n = 0; n < 16; ++n) {
        i16x8_t b = *(const i16x8_t*)(w2t + (n * 16 + mrow) * 256 + k);
        acc[n] = mfma16h(a, b, acc[n]);
      }
    }
#pragma unroll
    for (int n = 0; n < 16; ++n)
#pragma unroll
      for (int r = 0; r < 4; ++r) {
        int m = wv * 16 + quad * 4 + r;
        int col = n * 16 + mrow;
        float v = acc[n][r] + b2[col];
        v = v > 0.f ? v : 0.1f * v;
        X3[m][col] = f2h(v);
      }
  }
  __syncthreads();

  // stage 3: XF[128][128] = X3 @ W3 + b3 (fp32; overlays dead X2)
  float (*XF)[130] = (float (*)[130]) & X2[0][0];
  {
    f32x4_t acc[8];
#pragma unroll
    for (int n = 0; n < 8; ++n) acc[n] = zero4;
#pragma unroll
    for (int kb = 0; kb < 8; ++kb) {
      int k = kb * 32 + quad * 8;
      i16x8_t a = *(const i16x8_t*)&X3[wv * 16 + mrow][k];
#pragma unroll
      for (int n = 0; n < 8; ++n) {
        i16x8_t b = *(const i16x8_t*)(w3t + (n * 16 + mrow) * 256 + k);
        acc[n] = mfma16h(a, b, acc[n]);
      }
    }
#pragma unroll
    for (int n = 0; n < 8; ++n)
#pragma unroll
      for (int r = 0; r < 4; ++r) {
        int m = wv * 16 + quad * 4 + r;
        int col = n * 16 + mrow;
        XF[m][col] = acc[n][r] + b3[col];
      }
  }
  __syncthreads();

  // heads: cols 0:64 sigmoid; softmax over [64,72), [72,88), [88,128)
  if (tid < 128) {
    int row = tid;
    float* xr = XF[row];
    float* op = out + (size_t)(r0 + row) * 128;
    for (int cc = 0; cc < 64; ++cc) op[cc] = sigmoidf_(xr[cc]);
  } else if (tid < 256) {
    int row = tid - 128;
    float* xr = XF[row];
    float* op = out + (size_t)(r0 + row) * 128;
    const int s0s[3] = {64, 72, 88};
    const int s1s[3] = {72, 88, 128};
    for (int s = 0; s < 3; ++s) {
      int s0 = s0s[s], s1 = s1s[s];
      float mx = xr[s0];
      for (int q = s0 + 1; q < s1; ++q) mx = fmaxf(mx, xr[q]);
      float sum = 0.f;
      for (int q = s0; q < s1; ++q) { float e = __expf(xr[q] - mx); xr[q] = e; sum += e; }
      float inv = 1.f / sum;
      for (int q = s0; q < s1; ++q) op[q] = xr[q] * inv;
    }
  }
}

// ---- launch ----------------------------------------------------------------
extern "C" void kernel_launch(void* const* d_in, const int* in_sizes, int n_in,
                              void* d_out, int out_size, void* d_ws, size_t ws_size,
                              hipStream_t stream) {
  const float* x0   = (const float*)d_in[0];
  const float* Wi_f = (const float*)d_in[1];
  const float* bi_f = (const float*)d_in[2];
  const float* Wh_f = (const float*)d_in[3];
  const float* bh_f = (const float*)d_in[4];
  const float* Wi_r = (const float*)d_in[5];
  const float* bi_r = (const float*)d_in[6];
  const float* Wh_r = (const float*)d_in[7];
  const float* bh_r = (const float*)d_in[8];
  const float* W1 = (const float*)d_in[9];
  const float* b1 = (const float*)d_in[10];
  const float* W2 = (const float*)d_in[11];
  const float* b2 = (const float*)d_in[12];
  const float* W3 = (const float*)d_in[13];
  const float* b3 = (const float*)d_in[14];
  float* out = (float*)d_out;

  char* ws = (char*)d_ws;
  u16* w1t   = (u16*)(ws + 0);         // 262144 B
  u16* w2t   = (u16*)(ws + 262144);    // 131072 B
  u16* w3t   = (u16*)(ws + 393216);    // 65536 B
  u16* wpack = (u16*)(ws + 458752);    // 1572864 B
  u16* x1    = (u16*)(ws + 2031616);   // 67108864 B
  unsigned* flags = (unsigned*)(ws + 69140480);  // 32768 B

  hipLaunchKernelGGL(prep_wpack, dim3(3072), dim3(256), 0, stream,
                     Wi_f, Wh_f, Wi_r, Wh_r, wpack);
  hipLaunchKernelGGL(prep_small, dim3(896), dim3(256), 0, stream,
                     W1, W2, W3, w1t, w2t, w3t, flags);
  {
    void* params[8];
    params[0] = (void*)&x0;
    params[1] = (void*)&wpack;
    params[2] = (void*)&bi_f;
    params[3] = (void*)&bh_f;
    params[4] = (void*)&bi_r;
    params[5] = (void*)&bh_r;
    params[6] = (void*)&x1;
    params[7] = (void*)&flags;
    hipLaunchCooperativeKernel((const void*)lstm_kernel, dim3(256), dim3(512),
                               params, 0, stream);
  }
  hipLaunchKernelGGL(mlp_kernel, dim3(512), dim3(512), 0, stream,
                     x1, w1t, w2t, w3t, b1, b2, b3, out);
}

// Round 9
// 726.959 us; speedup vs baseline: 3.6885x; 1.0488x over previous
//
#include <hip/hip_runtime.h>

typedef unsigned short u16;
typedef unsigned long long u64;
typedef _Float16 f16x8_t __attribute__((ext_vector_type(8)));
typedef short    i16x8_t __attribute__((ext_vector_type(8)));
typedef short    i16x4_t __attribute__((ext_vector_type(4)));
typedef float    f32x4_t __attribute__((ext_vector_type(4)));

// force a loaded value to stay materialized in VGPRs (no remat/sinking)
#define PIN(x) asm volatile("" : "+v"(x))

// ---- helpers ---------------------------------------------------------------
static __device__ __forceinline__ u16 f2h(float f) {
  _Float16 h = (_Float16)f;  // RNE
  return __builtin_bit_cast(u16, h);
}
static __device__ __forceinline__ f32x4_t mfma16h(i16x8_t a, i16x8_t b, f32x4_t c) {
  return __builtin_amdgcn_mfma_f32_16x16x32_f16(
      __builtin_bit_cast(f16x8_t, a), __builtin_bit_cast(f16x8_t, b), c, 0, 0, 0);
}
static __device__ __forceinline__ float sigmoidf_(float x) { return 1.f / (1.f + __expf(-x)); }
static __device__ __forceinline__ float tanhf_(float x) { return 1.f - 2.f / (__expf(2.f * x) + 1.f); }

// true iff none of the four u16 lanes equals the sentinel 0x7FFF
static __device__ __forceinline__ bool no_sent(u64 v) {
  u64 x = v ^ 0x7FFF7FFF7FFF7FFFull;  // sentinel lane -> 0x0000
  return (((x - 0x0001000100010001ull) & ~x & 0x8000800080008000ull) == 0);
}

// ---- prep: LSTM weights pre-swizzled into MFMA fragment order --------------
// wpack[dir][tau][kb][lane][8]: tau = jb*4+g (jb = j-block, g = gate),
// kb in [0,12), lane = quad*16+mrow. Element e: n = g*256+jb*16+mrow,
// k = kb*32+quad*8+e; value = k<128 ? Wi[k][n] : Wh[k-128][n].
__global__ __launch_bounds__(256) void prep_wpack(const float* __restrict__ Wi_f,
                                                  const float* __restrict__ Wh_f,
                                                  const float* __restrict__ Wi_r,
                                                  const float* __restrict__ Wh_r,
                                                  u16* __restrict__ wpack) {
  int id = blockIdx.x * 256 + threadIdx.x;
  if (id >= 786432) return;  // 2*64*12*64*8
  int e = id & 7, r = id >> 3;
  int lane = r & 63; r >>= 6;
  int kb = r % 12; r /= 12;
  int tau = r & 63, dir = r >> 6;
  int mrow = lane & 15, quad = lane >> 4;
  int jb = tau >> 2, g = tau & 3;
  int n = g * 256 + jb * 16 + mrow;
  int k = kb * 32 + quad * 8 + e;
  const float* Wi = dir ? Wi_r : Wi_f;
  const float* Wh = dir ? Wh_r : Wh_f;
  float v = (k < 128) ? Wi[k * 1024 + n] : Wh[(k - 128) * 1024 + n];
  wpack[id] = f2h(v);
}

// ---- prep: poison x1 with the f16-NaN sentinel (re-run every launch) -------
// h values are sigmoid*tanh in [-1,1]; the bit pattern 0x7FFF is unreachable,
// so "!= sentinel" certifies the producer's store for this launch has landed.
__global__ __launch_bounds__(256) void poison_x1(uint4* __restrict__ x1v) {
  size_t id = (size_t)blockIdx.x * 256 + threadIdx.x;  // 2,097,152 threads
  const uint4 s = {0x7FFF7FFFu, 0x7FFF7FFFu, 0x7FFF7FFFu, 0x7FFF7FFFu};
  x1v[id * 2] = s;
  x1v[id * 2 + 1] = s;  // 32 B/thread -> 64 MB total
}

// ---- prep: MLP W^T in f16 (W1[512][256], W2[256][256], W3[256][128]) -------
__global__ __launch_bounds__(256) void prep_small(const float* __restrict__ W1,
                                                  const float* __restrict__ W2,
                                                  const float* __restrict__ W3,
                                                  u16* __restrict__ w1t,
                                                  u16* __restrict__ w2t,
                                                  u16* __restrict__ w3t) {
  int id = blockIdx.x * 256 + threadIdx.x;
  if (id < 131072) { int n = id >> 9, k = id & 511; w1t[id] = f2h(W1[k * 256 + n]); return; }
  id -= 131072;
  if (id < 65536) { int n = id >> 8, k = id & 255; w2t[id] = f2h(W2[k * 256 + n]); return; }
  id -= 65536;
  if (id < 32768) { int n = id >> 8, k = id & 255; w3t[id] = f2h(W3[k * 128 + n]); }
}

// ---- bidirectional LSTM v12: sentinel h-exchange (1 LLC transit, 2 barriers)
// 256 blocks = q(4 gate-slices) x dir(2) x grp(32 batch-groups of 16 rows).
// Block owns gate-cols tau_g in [16q,16q+16): Wh slice (128 KB) LDS-resident,
// Wi slice in 32 pinned VGPR/wave. v11's residual cost was the sync chain:
// store-ack -> flag RMW -> poll -> load = ~4 LLC transits + 4 barriers/step.
// v12: x1 is poisoned with f16-NaN 0x7FFF each launch; producers just issue
// relaxed atomic h-stores (write-through to LLC, no drain, no flag); each
// consumer thread retry-loads its own 16 B until sentinel-free. Torn views
// (one 4B half new, other poison) are caught by the per-u16 check. Barriers
// per step: 2 (ah-ready / gbuf-ready); reuse-ordering proofs in comments.
// Numerics bit-identical to v8..v11 (same MFMA order, same f16 points).
__global__ __launch_bounds__(512, 2) void lstm_kernel(
    const float* __restrict__ x0, const u16* __restrict__ wpack,
    const float* __restrict__ bi_f, const float* __restrict__ bh_f,
    const float* __restrict__ bi_r, const float* __restrict__ bh_r,
    u16* __restrict__ x1) {
  __shared__ __align__(16) u16 lwh[16][8][64][8];  // 128 KB Wh kb4..11, 16 taus
  __shared__ __align__(16) u16 ah[16][256];        // 8 KB h panel, XOR-swizzled
  __shared__ __align__(16) float gbuf[16][260];    // gate pre-activations (f32)

  const int tid = threadIdx.x;
  const int lane = tid & 63;
  const int w = tid >> 6;             // wave 0..7
  const int bid = blockIdx.x;
  const int q = bid >> 6;             // gate-slice 0..3
  const int rem = bid & 63;
  const int dir = rem >> 5;
  const int grp = rem & 31;
  const int b0 = grp * 16;
  const u16* wpk = wpack + (size_t)dir * (64 * 12 * 64 * 8);
  const float* bi = dir ? bi_r : bi_f;
  const float* bh = dir ? bh_r : bh_f;
  const int mrow = lane & 15, quad = lane >> 4;
  const int tauL0 = 2 * w;            // this wave's 2 local n-tiles

  // biases for the wave's 2 taus
  float bias2[2];
#pragma unroll
  for (int lt = 0; lt < 2; ++lt) {
    int tau_g = 16 * q + tauL0 + lt;
    int n = (tau_g & 3) * 256 + (tau_g >> 2) * 16 + mrow;
    bias2[lt] = bi[n] + bh[n];
  }

  // Wh kb4..11 for the block's 16 taus -> LDS (8192 frags of 16 B)
#pragma unroll
  for (int r = 0; r < 16; ++r) {
    int d = r * 512 + tid;
    int ltau = d >> 9, lkb = (d >> 6) & 7, ll = d & 63;
    *(i16x8_t*)&lwh[ltau][lkb][ll][0] =
        *(const i16x8_t*)(wpk + (((size_t)(16 * q + ltau) * 12 + 4 + lkb) * 64 + ll) * 8);
  }
  // Wi kb0..3 for the wave's 2 taus -> registers (32 VGPR), pinned
  i16x8_t wir[2][4];
#pragma unroll
  for (int lt = 0; lt < 2; ++lt)
#pragma unroll
    for (int kb = 0; kb < 4; ++kb) {
      wir[lt][kb] =
          *(const i16x8_t*)(wpk + (((size_t)(16 * q + tauL0 + lt) * 12 + kb) * 64 + lane) * 8);
      PIN(wir[lt][kb]);
    }
  __syncthreads();  // lwh ready

  // c-state: thread owns 2 adjacent cells (row = tid>>5, jj = 2*(tid&31)+e)
  const int crow = tid >> 5;
  const int cj0 = (tid & 31) * 2;
  float c0 = 0.f, c1 = 0.f;

  // per-lane global base for x-fragment loads (direct, pre-stage)
  const float* xfrag_base = x0 + (size_t)(b0 + mrow) * 16384 + quad * 8;
  // h staging: 16B/thread, coalesced rows; LDS dst is XOR-swizzled
  const int fm = tid >> 5, fj = (tid & 31) * 8;
  const u16* hstage_src = x1 + (size_t)(b0 + fm) * 65536 + dir * 256 + fj;
  u16* ah_dst = &ah[fm][fj ^ ((fm & 7) << 3)];

  for (int t = 0; t < 128; ++t) {
    const int teff = dir ? 127 - t : t;

    // x fragments: direct from x0 (L2-resident; no cache maintenance anywhere)
    i16x8_t afx[4];
    {
      const float* xp = xfrag_base + (size_t)teff * 128;
#pragma unroll
      for (int kb = 0; kb < 4; ++kb) {
        float4 va = *(const float4*)(xp + kb * 32);
        float4 vb = *(const float4*)(xp + kb * 32 + 4);
        i16x8_t v;
        v[0] = (short)f2h(va.x); v[1] = (short)f2h(va.y);
        v[2] = (short)f2h(va.z); v[3] = (short)f2h(va.w);
        v[4] = (short)f2h(vb.x); v[5] = (short)f2h(vb.y);
        v[6] = (short)f2h(vb.z); v[7] = (short)f2h(vb.w);
        afx[kb] = v;
      }
    }
    // x-projection MFMAs BEFORE staging (overlap with producers finishing)
    f32x4_t acc[2];
#pragma unroll
    for (int lt = 0; lt < 2; ++lt) {
      float bv = bias2[lt];
      f32x4_t a = {bv, bv, bv, bv};
      a = mfma16h(afx[0], wir[lt][0], a);
      a = mfma16h(afx[1], wir[lt][1], a);
      a = mfma16h(afx[2], wir[lt][2], a);
      a = mfma16h(afx[3], wir[lt][3], a);
      acc[lt] = a;
    }

    // stage h_{t-1}: per-thread retry until sentinel-free (LLC-direct loads).
    // ah overwrite is safe: all afh reads of step t-1 precede barrier B(t-1),
    // and this stage follows B(t-1) in program order on every thread.
    if (t > 0) {
      const u64* hsrc = (const u64*)(hstage_src + (size_t)(t - 1) * 512);
      u64 h0 = __hip_atomic_load(hsrc, __ATOMIC_RELAXED, __HIP_MEMORY_SCOPE_AGENT);
      u64 h1 = __hip_atomic_load(hsrc + 1, __ATOMIC_RELAXED, __HIP_MEMORY_SCOPE_AGENT);
      unsigned iter = 0;
      while (!(no_sent(h0) && no_sent(h1))) {
        __builtin_amdgcn_s_sleep(1);
        if (!no_sent(h0))
          h0 = __hip_atomic_load(hsrc, __ATOMIC_RELAXED, __HIP_MEMORY_SCOPE_AGENT);
        if (!no_sent(h1))
          h1 = __hip_atomic_load(hsrc + 1, __ATOMIC_RELAXED, __HIP_MEMORY_SCOPE_AGENT);
        if (++iter > (1u << 20)) break;  // fail-safe: bug -> wrong answer, not hang
      }
      ((u64*)ah_dst)[0] = h0;
      ((u64*)ah_dst)[1] = h1;
    }
    __syncthreads();  // (A) ah ready

    if (t > 0) {  // h-part MFMAs: conflict-free swizzled ds_read_b128
      i16x8_t afh[8];
#pragma unroll
      for (int kb = 0; kb < 8; ++kb)
        afh[kb] = *(const i16x8_t*)&ah[mrow][(kb * 32 + quad * 8) ^ ((mrow & 7) << 3)];
#pragma unroll
      for (int lt = 0; lt < 2; ++lt) {
#pragma unroll
        for (int kb = 0; kb < 8; ++kb)
          acc[lt] = mfma16h(afh[kb], *(const i16x8_t*)&lwh[tauL0 + lt][kb][lane][0], acc[lt]);
      }
    }
    // write gate pre-activations. gbuf overwrite is safe: all gate reads of
    // step t-1 precede barrier A(t) (gate -> stage -> A in program order).
#pragma unroll
    for (int lt = 0; lt < 2; ++lt) {
      int col = (tauL0 + lt) * 16 + mrow;
#pragma unroll
      for (int r = 0; r < 4; ++r) gbuf[quad * 4 + r][col] = acc[lt][r];
    }
    __syncthreads();  // (B) gbuf ready

    // gate phase: 2 cells/thread; col(g) = jb_l*64 + g*16 + mr
    {
      float hv[2];
#pragma unroll
      for (int e = 0; e < 2; ++e) {
        int jj = cj0 + e;
        int base = (jj >> 4) * 64 + (jj & 15);
        float fg = gbuf[crow][base];
        float ig = gbuf[crow][base + 16];
        float ag = gbuf[crow][base + 32];
        float og = gbuf[crow][base + 48];
        float cc = e ? c1 : c0;
        float cv = sigmoidf_(fg) * cc + sigmoidf_(ig) * tanhf_(ag);
        if (e) c1 = cv; else c0 = cv;
        hv[e] = sigmoidf_(og) * tanhf_(cv);
      }
      unsigned pack = (unsigned)f2h(hv[0]) | ((unsigned)f2h(hv[1]) << 16);
      unsigned* hp = (unsigned*)(x1 + ((size_t)((b0 + crow) * 128 + t)) * 512 +
                                 dir * 256 + 64 * q + cj0);
      // write-through to LLC; consumers certify arrival via sentinel check
      __hip_atomic_store(hp, pack, __ATOMIC_RELAXED, __HIP_MEMORY_SCOPE_AGENT);
    }
    // no trailing barrier, no flag: the store IS the signal
  }
}

// ---- fused MLP + heads (unchanged — passing) ------------------------------
__global__ __launch_bounds__(512, 1) void mlp_kernel(
    const u16* __restrict__ x1, const u16* __restrict__ w1t,
    const u16* __restrict__ w2t, const u16* __restrict__ w3t,
    const float* __restrict__ b1, const float* __restrict__ b2,
    const float* __restrict__ b3, float* __restrict__ out) {
  __shared__ __align__(16) u16 X2[128][264];
  __shared__ __align__(16) u16 X3[128][264];
  const int tid = threadIdx.x;
  const int lane = tid & 63, wv = tid >> 6;
  const int mrow = lane & 15, quad = lane >> 4;
  const int r0 = blockIdx.x * 128;
  const f32x4_t zero4 = {0.f, 0.f, 0.f, 0.f};

  // stage 1: X2[128][256] = leaky(x1[128,512] @ W1 + b1)
  {
    f32x4_t acc[16];
#pragma unroll
    for (int n = 0; n < 16; ++n) acc[n] = zero4;
    for (int kb = 0; kb < 16; ++kb) {
      int k = kb * 32 + quad * 8;
      i16x8_t a = *(const i16x8_t*)(x1 + (size_t)(r0 + wv * 16 + mrow) * 512 + k);
#pragma unroll
      for (int n = 0; n < 16; ++n) {
        i16x8_t b = *(const i16x8_t*)(w1t + (n * 16 + mrow) * 512 + k);
        acc[n] = mfma16h(a, b, acc[n]);
      }
    }
#pragma unroll
    for (int n = 0; n < 16; ++n)
#pragma unroll
      for (int r = 0; r < 4; ++r) {
        int m = wv * 16 + quad * 4 + r;
        int col = n * 16 + mrow;
        float v = acc[n][r] + b1[col];
        v = v > 0.f ? v : 0.1f * v;
        X2[m][col] = f2h(v);
      }
  }
  __syncthreads();

  // stage 2: X3[128][256] = leaky(X2 @ W2 + b2), K=256
  {
    f32x4_t acc[16];
#pragma unroll
    for (int n = 0; n < 16; ++n) acc[n] = zero4;
#pragma unroll
    for (int kb = 0; kb < 8; ++kb) {
      int k = kb * 32 + quad * 8;
      i16x8_t a = *(const i16x8_t*)&X2[wv * 16 + mrow][k];
#pragma unroll
      for (int n = 0; n < 16; ++n) {
        i16x8_t b = *(const i16x8_t*)(w2t + (n * 16 + mrow) * 256 + k);
        acc[n] = mfma16h(a, b, acc[n]);
      }
    }
#pragma unroll
    for (int n = 0; n < 16; ++n)
#pragma unroll
      for (int r = 0; r < 4; ++r) {
        int m = wv * 16 + quad * 4 + r;
        int col = n * 16 + mrow;
        float v = acc[n][r] + b2[col];
        v = v > 0.f ? v : 0.1f * v;
        X3[m][col] = f2h(v);
      }
  }
  __syncthreads();

  // stage 3: XF[128][128] = X3 @ W3 + b3 (fp32; overlays dead X2)
  float (*XF)[130] = (float (*)[130]) & X2[0][0];
  {
    f32x4_t acc[8];
#pragma unroll
    for (int n = 0; n < 8; ++n) acc[n] = zero4;
#pragma unroll
    for (int kb = 0; kb < 8; ++kb) {
      int k = kb * 32 + quad * 8;
      i16x8_t a = *(const i16x8_t*)&X3[wv * 16 + mrow][k];
#pragma unroll
      for (int n = 0; n < 8; ++n) {
        i16x8_t b = *(const i16x8_t*)(w3t + (n * 16 + mrow) * 256 + k);
        acc[n] = mfma16h(a, b, acc[n]);
      }
    }
#pragma unroll
    for (int n = 0; n < 8; ++n)
#pragma unroll
      for (int r = 0; r < 4; ++r) {
        int m = wv * 16 + quad * 4 + r;
        int col = n * 16 + mrow;
        XF[m][col] = acc[n][r] + b3[col];
      }
  }
  __syncthreads();

  // heads: cols 0:64 sigmoid; softmax over [64,72), [72,88), [88,128)
  if (tid < 128) {
    int row = tid;
    float* xr = XF[row];
    float* op = out + (size_t)(r0 + row) * 128;
    for (int cc = 0; cc < 64; ++cc) op[cc] = sigmoidf_(xr[cc]);
  } else if (tid < 256) {
    int row = tid - 128;
    float* xr = XF[row];
    float* op = out + (size_t)(r0 + row) * 128;
    const int s0s[3] = {64, 72, 88};
    const int s1s[3] = {72, 88, 128};
    for (int s = 0; s < 3; ++s) {
      int s0 = s0s[s], s1 = s1s[s];
      float mx = xr[s0];
      for (int q = s0 + 1; q < s1; ++q) mx = fmaxf(mx, xr[q]);
      float sum = 0.f;
      for (int q = s0; q < s1; ++q) { float e = __expf(xr[q] - mx); xr[q] = e; sum += e; }
      float inv = 1.f / sum;
      for (int q = s0; q < s1; ++q) op[q] = xr[q] * inv;
    }
  }
}

// ---- launch ----------------------------------------------------------------
extern "C" void kernel_launch(void* const* d_in, const int* in_sizes, int n_in,
                              void* d_out, int out_size, void* d_ws, size_t ws_size,
                              hipStream_t stream) {
  const float* x0   = (const float*)d_in[0];
  const float* Wi_f = (const float*)d_in[1];
  const float* bi_f = (const float*)d_in[2];
  const float* Wh_f = (const float*)d_in[3];
  const float* bh_f = (const float*)d_in[4];
  const float* Wi_r = (const float*)d_in[5];
  const float* bi_r = (const float*)d_in[6];
  const float* Wh_r = (const float*)d_in[7];
  const float* bh_r = (const float*)d_in[8];
  const float* W1 = (const float*)d_in[9];
  const float* b1 = (const float*)d_in[10];
  const float* W2 = (const float*)d_in[11];
  const float* b2 = (const float*)d_in[12];
  const float* W3 = (const float*)d_in[13];
  const float* b3 = (const float*)d_in[14];
  float* out = (float*)d_out;

  char* ws = (char*)d_ws;
  u16* w1t   = (u16*)(ws + 0);         // 262144 B
  u16* w2t   = (u16*)(ws + 262144);    // 131072 B
  u16* w3t   = (u16*)(ws + 393216);    // 65536 B
  u16* wpack = (u16*)(ws + 458752);    // 1572864 B
  u16* x1    = (u16*)(ws + 2031616);   // 67108864 B

  hipLaunchKernelGGL(prep_wpack, dim3(3072), dim3(256), 0, stream,
                     Wi_f, Wh_f, Wi_r, Wh_r, wpack);
  hipLaunchKernelGGL(poison_x1, dim3(8192), dim3(256), 0, stream, (uint4*)x1);
  hipLaunchKernelGGL(prep_small, dim3(896), dim3(256), 0, stream,
                     W1, W2, W3, w1t, w2t, w3t);
  {
    void* params[7];
    params[0] = (void*)&x0;
    params[1] = (void*)&wpack;
    params[2] = (void*)&bi_f;
    params[3] = (void*)&bh_f;
    params[4] = (void*)&bi_r;
    params[5] = (void*)&bh_r;
    params[6] = (void*)&x1;
    hipLaunchCooperativeKernel((const void*)lstm_kernel, dim3(256), dim3(512),
                               params, 0, stream);
  }
  hipLaunchKernelGGL(mlp_kernel, dim3(512), dim3(512), 0, stream,
                     x1, w1t, w2t, w3t, b1, b2, b3, out);
}

// Round 10
// 719.983 us; speedup vs baseline: 3.7242x; 1.0097x over previous
//
#include <hip/hip_runtime.h>

typedef unsigned short u16;
typedef unsigned long long u64;
typedef _Float16 f16x8_t __attribute__((ext_vector_type(8)));
typedef short    i16x8_t __attribute__((ext_vector_type(8)));
typedef short    i16x4_t __attribute__((ext_vector_type(4)));
typedef float    f32x4_t __attribute__((ext_vector_type(4)));

// force a loaded value to stay materialized in VGPRs (no remat/sinking)
#define PIN(x) asm volatile("" : "+v"(x))

// ---- helpers ---------------------------------------------------------------
static __device__ __forceinline__ u16 f2h(float f) {
  _Float16 h = (_Float16)f;  // RNE
  return __builtin_bit_cast(u16, h);
}
static __device__ __forceinline__ f32x4_t mfma16h(i16x8_t a, i16x8_t b, f32x4_t c) {
  return __builtin_amdgcn_mfma_f32_16x16x32_f16(
      __builtin_bit_cast(f16x8_t, a), __builtin_bit_cast(f16x8_t, b), c, 0, 0, 0);
}
static __device__ __forceinline__ float sigmoidf_(float x) { return 1.f / (1.f + __expf(-x)); }
static __device__ __forceinline__ float tanhf_(float x) { return 1.f - 2.f / (__expf(2.f * x) + 1.f); }

// true iff none of the four u16 lanes equals the sentinel 0x7FFF
static __device__ __forceinline__ bool no_sent(u64 v) {
  u64 x = v ^ 0x7FFF7FFF7FFF7FFFull;  // sentinel lane -> 0x0000
  return (((x - 0x0001000100010001ull) & ~x & 0x8000800080008000ull) == 0);
}
static __device__ __forceinline__ bool ok16(uint4 v) {
  u64 a = ((u64)v.y << 32) | v.x;
  u64 b = ((u64)v.w << 32) | v.z;
  return no_sent(a) && no_sent(b);
}

// 16B LLC-coherent load: plain pipelined load that bypasses L1/L2 (sc0 sc1).
// NOT an atomic op -- coalesces into 64B LLC line requests at full rate.
static __device__ __forceinline__ uint4 llc_load16(const uint4* p) {
  uint4 r;
  asm volatile("global_load_dwordx4 %0, %1, off sc0 sc1\n\t"
               "s_waitcnt vmcnt(0)"
               : "=&v"(r) : "v"(p) : "memory");
  return r;
}
// 4B LLC write-through store (bypasses L1/L2, lands at the coherence point)
static __device__ __forceinline__ void llc_store4(unsigned* p, unsigned v) {
  asm volatile("global_store_dword %0, %1, off sc0 sc1" :: "v"(p), "v"(v) : "memory");
}

// ---- prep: LSTM weights pre-swizzled into MFMA fragment order --------------
// wpack[dir][tau][kb][lane][8]: tau = jb*4+g (jb = j-block, g = gate),
// kb in [0,12), lane = quad*16+mrow. Element e: n = g*256+jb*16+mrow,
// k = kb*32+quad*8+e; value = k<128 ? Wi[k][n] : Wh[k-128][n].
__global__ __launch_bounds__(256) void prep_wpack(const float* __restrict__ Wi_f,
                                                  const float* __restrict__ Wh_f,
                                                  const float* __restrict__ Wi_r,
                                                  const float* __restrict__ Wh_r,
                                                  u16* __restrict__ wpack) {
  int id = blockIdx.x * 256 + threadIdx.x;
  if (id >= 786432) return;  // 2*64*12*64*8
  int e = id & 7, r = id >> 3;
  int lane = r & 63; r >>= 6;
  int kb = r % 12; r /= 12;
  int tau = r & 63, dir = r >> 6;
  int mrow = lane & 15, quad = lane >> 4;
  int jb = tau >> 2, g = tau & 3;
  int n = g * 256 + jb * 16 + mrow;
  int k = kb * 32 + quad * 8 + e;
  const float* Wi = dir ? Wi_r : Wi_f;
  const float* Wh = dir ? Wh_r : Wh_f;
  float v = (k < 128) ? Wi[k * 1024 + n] : Wh[(k - 128) * 1024 + n];
  wpack[id] = f2h(v);
}

// ---- prep: poison x1 with the f16-NaN sentinel (re-run every launch) -------
// h values are sigmoid*tanh in [-1,1]; the bit pattern 0x7FFF is unreachable,
// so "!= sentinel" certifies the producer's store for this launch has landed.
// End-of-kernel implicit L2 writeback puts the poison in the LLC before lstm
// starts (v12-proven).
__global__ __launch_bounds__(256) void poison_x1(uint4* __restrict__ x1v) {
  size_t id = (size_t)blockIdx.x * 256 + threadIdx.x;  // 2,097,152 threads
  const uint4 s = {0x7FFF7FFFu, 0x7FFF7FFFu, 0x7FFF7FFFu, 0x7FFF7FFFu};
  x1v[id * 2] = s;
  x1v[id * 2 + 1] = s;  // 32 B/thread -> 64 MB total
}

// ---- prep: MLP W^T in f16 (W1[512][256], W2[256][256], W3[256][128]) -------
__global__ __launch_bounds__(256) void prep_small(const float* __restrict__ W1,
                                                  const float* __restrict__ W2,
                                                  const float* __restrict__ W3,
                                                  u16* __restrict__ w1t,
                                                  u16* __restrict__ w2t,
                                                  u16* __restrict__ w3t) {
  int id = blockIdx.x * 256 + threadIdx.x;
  if (id < 131072) { int n = id >> 9, k = id & 511; w1t[id] = f2h(W1[k * 256 + n]); return; }
  id -= 131072;
  if (id < 65536) { int n = id >> 8, k = id & 255; w2t[id] = f2h(W2[k * 256 + n]); return; }
  id -= 65536;
  if (id < 32768) { int n = id >> 8, k = id & 255; w3t[id] = f2h(W3[k * 128 + n]); }
}

// ---- bidirectional LSTM v13: v12 with normal-instruction LLC exchange ------
// 256 blocks = q(4 gate-slices) x dir(2) x grp(32 batch-groups of 16 rows).
// Block owns gate-cols tau_g in [16q,16q+16): Wh slice (128 KB) LDS-resident,
// Wi slice in 32 pinned VGPR/wave. v12's residual wall: staging used AGENT
// atomic loads (8B each, 2/thread = 262K discrete serialized LLC atomic ops
// per step chip-wide; no line coalescing, no pipelining). v13 keeps the
// sentinel protocol but swaps the memory path to plain sc0|sc1 instructions:
//   consumer: ONE global_load_dwordx4 sc0 sc1 per thread (16B, line-coalesced
//             4:1, pipelined across waves), retried while any u16 == 0x7FFF;
//   producer: global_store_dword sc0 sc1 (write-through, no atomic path).
// Atomicity is unnecessary -- freshness (L1/L2 bypass) + per-u16 sentinel
// check handle ordering and tearing. Barriers/step: 2. Numerics bit-identical
// to v8..v12 (same MFMA order, same f16 conversion points).
__global__ __launch_bounds__(512, 2) void lstm_kernel(
    const float* __restrict__ x0, const u16* __restrict__ wpack,
    const float* __restrict__ bi_f, const float* __restrict__ bh_f,
    const float* __restrict__ bi_r, const float* __restrict__ bh_r,
    u16* __restrict__ x1) {
  __shared__ __align__(16) u16 lwh[16][8][64][8];  // 128 KB Wh kb4..11, 16 taus
  __shared__ __align__(16) u16 ah[16][256];        // 8 KB h panel, XOR-swizzled
  __shared__ __align__(16) float gbuf[16][260];    // gate pre-activations (f32)

  const int tid = threadIdx.x;
  const int lane = tid & 63;
  const int w = tid >> 6;             // wave 0..7
  const int bid = blockIdx.x;
  const int q = bid >> 6;             // gate-slice 0..3
  const int rem = bid & 63;
  const int dir = rem >> 5;
  const int grp = rem & 31;
  const int b0 = grp * 16;
  const u16* wpk = wpack + (size_t)dir * (64 * 12 * 64 * 8);
  const float* bi = dir ? bi_r : bi_f;
  const float* bh = dir ? bh_r : bh_f;
  const int mrow = lane & 15, quad = lane >> 4;
  const int tauL0 = 2 * w;            // this wave's 2 local n-tiles

  // biases for the wave's 2 taus
  float bias2[2];
#pragma unroll
  for (int lt = 0; lt < 2; ++lt) {
    int tau_g = 16 * q + tauL0 + lt;
    int n = (tau_g & 3) * 256 + (tau_g >> 2) * 16 + mrow;
    bias2[lt] = bi[n] + bh[n];
  }

  // Wh kb4..11 for the block's 16 taus -> LDS (8192 frags of 16 B)
#pragma unroll
  for (int r = 0; r < 16; ++r) {
    int d = r * 512 + tid;
    int ltau = d >> 9, lkb = (d >> 6) & 7, ll = d & 63;
    *(i16x8_t*)&lwh[ltau][lkb][ll][0] =
        *(const i16x8_t*)(wpk + (((size_t)(16 * q + ltau) * 12 + 4 + lkb) * 64 + ll) * 8);
  }
  // Wi kb0..3 for the wave's 2 taus -> registers (32 VGPR), pinned
  i16x8_t wir[2][4];
#pragma unroll
  for (int lt = 0; lt < 2; ++lt)
#pragma unroll
    for (int kb = 0; kb < 4; ++kb) {
      wir[lt][kb] =
          *(const i16x8_t*)(wpk + (((size_t)(16 * q + tauL0 + lt) * 12 + kb) * 64 + lane) * 8);
      PIN(wir[lt][kb]);
    }
  __syncthreads();  // lwh ready

  // c-state: thread owns 2 adjacent cells (row = tid>>5, jj = 2*(tid&31)+e)
  const int crow = tid >> 5;
  const int cj0 = (tid & 31) * 2;
  float c0 = 0.f, c1 = 0.f;

  // per-lane global base for x-fragment loads (direct, pre-stage)
  const float* xfrag_base = x0 + (size_t)(b0 + mrow) * 16384 + quad * 8;
  // h staging: 16B/thread, coalesced rows; LDS dst is XOR-swizzled
  const int fm = tid >> 5, fj = (tid & 31) * 8;
  const u16* hstage_src = x1 + (size_t)(b0 + fm) * 65536 + dir * 256 + fj;
  u16* ah_dst = &ah[fm][fj ^ ((fm & 7) << 3)];

  for (int t = 0; t < 128; ++t) {
    const int teff = dir ? 127 - t : t;

    // x fragments: direct from x0 (read-only, normal cached loads)
    i16x8_t afx[4];
    {
      const float* xp = xfrag_base + (size_t)teff * 128;
#pragma unroll
      for (int kb = 0; kb < 4; ++kb) {
        float4 va = *(const float4*)(xp + kb * 32);
        float4 vb = *(const float4*)(xp + kb * 32 + 4);
        i16x8_t v;
        v[0] = (short)f2h(va.x); v[1] = (short)f2h(va.y);
        v[2] = (short)f2h(va.z); v[3] = (short)f2h(va.w);
        v[4] = (short)f2h(vb.x); v[5] = (short)f2h(vb.y);
        v[6] = (short)f2h(vb.z); v[7] = (short)f2h(vb.w);
        afx[kb] = v;
      }
    }
    // x-projection MFMAs BEFORE staging (overlap with producers finishing)
    f32x4_t acc[2];
#pragma unroll
    for (int lt = 0; lt < 2; ++lt) {
      float bv = bias2[lt];
      f32x4_t a = {bv, bv, bv, bv};
      a = mfma16h(afx[0], wir[lt][0], a);
      a = mfma16h(afx[1], wir[lt][1], a);
      a = mfma16h(afx[2], wir[lt][2], a);
      a = mfma16h(afx[3], wir[lt][3], a);
      acc[lt] = a;
    }

    // stage h_{t-1}: one 16B LLC-coherent load per thread, retry on sentinel.
    // ah overwrite is safe: all afh reads of step t-1 precede barrier B(t-1),
    // and this stage follows B(t-1) in program order on every thread.
    if (t > 0) {
      const uint4* hsrc = (const uint4*)(hstage_src + (size_t)(t - 1) * 512);
      uint4 hv4 = llc_load16(hsrc);
      unsigned iter = 0;
      while (!ok16(hv4)) {
        __builtin_amdgcn_s_sleep(1);
        hv4 = llc_load16(hsrc);
        if (++iter > (1u << 20)) break;  // fail-safe: bug -> wrong answer, not hang
      }
      *(uint4*)ah_dst = hv4;
    }
    __syncthreads();  // (A) ah ready

    if (t > 0) {  // h-part MFMAs: conflict-free swizzled ds_read_b128
      i16x8_t afh[8];
#pragma unroll
      for (int kb = 0; kb < 8; ++kb)
        afh[kb] = *(const i16x8_t*)&ah[mrow][(kb * 32 + quad * 8) ^ ((mrow & 7) << 3)];
#pragma unroll
      for (int lt = 0; lt < 2; ++lt) {
#pragma unroll
        for (int kb = 0; kb < 8; ++kb)
          acc[lt] = mfma16h(afh[kb], *(const i16x8_t*)&lwh[tauL0 + lt][kb][lane][0], acc[lt]);
      }
    }
    // write gate pre-activations. gbuf overwrite is safe: all gate reads of
    // step t-1 precede barrier A(t) (gate -> stage -> A in program order).
#pragma unroll
    for (int lt = 0; lt < 2; ++lt) {
      int col = (tauL0 + lt) * 16 + mrow;
#pragma unroll
      for (int r = 0; r < 4; ++r) gbuf[quad * 4 + r][col] = acc[lt][r];
    }
    __syncthreads();  // (B) gbuf ready

    // gate phase: 2 cells/thread; col(g) = jb_l*64 + g*16 + mr
    {
      float hv[2];
#pragma unroll
      for (int e = 0; e < 2; ++e) {
        int jj = cj0 + e;
        int base = (jj >> 4) * 64 + (jj & 15);
        float fg = gbuf[crow][base];
        float ig = gbuf[crow][base + 16];
        float ag = gbuf[crow][base + 32];
        float og = gbuf[crow][base + 48];
        float cc = e ? c1 : c0;
        float cv = sigmoidf_(fg) * cc + sigmoidf_(ig) * tanhf_(ag);
        if (e) c1 = cv; else c0 = cv;
        hv[e] = sigmoidf_(og) * tanhf_(cv);
      }
      unsigned pack = (unsigned)f2h(hv[0]) | ((unsigned)f2h(hv[1]) << 16);
      unsigned* hp = (unsigned*)(x1 + ((size_t)((b0 + crow) * 128 + t)) * 512 +
                                 dir * 256 + 64 * q + cj0);
      // plain write-through to LLC; consumers certify arrival via sentinel
      llc_store4(hp, pack);
    }
    // no trailing barrier, no flag: the store IS the signal
  }
}

// ---- fused MLP + heads (unchanged — passing) ------------------------------
__global__ __launch_bounds__(512, 1) void mlp_kernel(
    const u16* __restrict__ x1, const u16* __restrict__ w1t,
    const u16* __restrict__ w2t, const u16* __restrict__ w3t,
    const float* __restrict__ b1, const float* __restrict__ b2,
    const float* __restrict__ b3, float* __restrict__ out) {
  __shared__ __align__(16) u16 X2[128][264];
  __shared__ __align__(16) u16 X3[128][264];
  const int tid = threadIdx.x;
  const int lane = tid & 63, wv = tid >> 6;
  const int mrow = lane & 15, quad = lane >> 4;
  const int r0 = blockIdx.x * 128;
  const f32x4_t zero4 = {0.f, 0.f, 0.f, 0.f};

  // stage 1: X2[128][256] = leaky(x1[128,512] @ W1 + b1)
  {
    f32x4_t acc[16];
#pragma unroll
    for (int n = 0; n < 16; ++n) acc[n] = zero4;
    for (int kb = 0; kb < 16; ++kb) {
      int k = kb * 32 + quad * 8;
      i16x8_t a = *(const i16x8_t*)(x1 + (size_t)(r0 + wv * 16 + mrow) * 512 + k);
#pragma unroll
      for (int n = 0; n < 16; ++n) {
        i16x8_t b = *(const i16x8_t*)(w1t + (n * 16 + mrow) * 512 + k);
        acc[n] = mfma16h(a, b, acc[n]);
      }
    }
#pragma unroll
    for (int n = 0; n < 16; ++n)
#pragma unroll
      for (int r = 0; r < 4; ++r) {
        int m = wv * 16 + quad * 4 + r;
        int col = n * 16 + mrow;
        float v = acc[n][r] + b1[col];
        v = v > 0.f ? v : 0.1f * v;
        X2[m][col] = f2h(v);
      }
  }
  __syncthreads();

  // stage 2: X3[128][256] = leaky(X2 @ W2 + b2), K=256
  {
    f32x4_t acc[16];
#pragma unroll
    for (int n = 0; n < 16; ++n) acc[n] = zero4;
#pragma unroll
    for (int kb = 0; kb < 8; ++kb) {
      int k = kb * 32 + quad * 8;
      i16x8_t a = *(const i16x8_t*)&X2[wv * 16 + mrow][k];
#pragma unroll
      for (int n = 0; n < 16; ++n) {
        i16x8_t b = *(const i16x8_t*)(w2t + (n * 16 + mrow) * 256 + k);
        acc[n] = mfma16h(a, b, acc[n]);
      }
    }
#pragma unroll
    for (int n = 0; n < 16; ++n)
#pragma unroll
      for (int r = 0; r < 4; ++r) {
        int m = wv * 16 + quad * 4 + r;
        int col = n * 16 + mrow;
        float v = acc[n][r] + b2[col];
        v = v > 0.f ? v : 0.1f * v;
        X3[m][col] = f2h(v);
      }
  }
  __syncthreads();

  // stage 3: XF[128][128] = X3 @ W3 + b3 (fp32; overlays dead X2)
  float (*XF)[130] = (float (*)[130]) & X2[0][0];
  {
    f32x4_t acc[8];
#pragma unroll
    for (int n = 0; n < 8; ++n) acc[n] = zero4;
#pragma unroll
    for (int kb = 0; kb < 8; ++kb) {
      int k = kb * 32 + quad * 8;
      i16x8_t a = *(const i16x8_t*)&X3[wv * 16 + mrow][k];
#pragma unroll
      for (int n = 0; n < 8; ++n) {
        i16x8_t b = *(const i16x8_t*)(w3t + (n * 16 + mrow) * 256 + k);
        acc[n] = mfma16h(a, b, acc[n]);
      }
    }
#pragma unroll
    for (int n = 0; n < 8; ++n)
#pragma unroll
      for (int r = 0; r < 4; ++r) {
        int m = wv * 16 + quad * 4 + r;
        int col = n * 16 + mrow;
        XF[m][col] = acc[n][r] + b3[col];
      }
  }
  __syncthreads();

  // heads: cols 0:64 sigmoid; softmax over [64,72), [72,88), [88,128)
  if (tid < 128) {
    int row = tid;
    float* xr = XF[row];
    float* op = out + (size_t)(r0 + row) * 128;
    for (int cc = 0; cc < 64; ++cc) op[cc] = sigmoidf_(xr[cc]);
  } else if (tid < 256) {
    int row = tid - 128;
    float* xr = XF[row];
    float* op = out + (size_t)(r0 + row) * 128;
    const int s0s[3] = {64, 72, 88};
    const int s1s[3] = {72, 88, 128};
    for (int s = 0; s < 3; ++s) {
      int s0 = s0s[s], s1 = s1s[s];
      float mx = xr[s0];
      for (int q = s0 + 1; q < s1; ++q) mx = fmaxf(mx, xr[q]);
      float sum = 0.f;
      for (int q = s0; q < s1; ++q) { float e = __expf(xr[q] - mx); xr[q] = e; sum += e; }
      float inv = 1.f / sum;
      for (int q = s0; q < s1; ++q) op[q] = xr[q] * inv;
    }
  }
}

// ---- launch ----------------------------------------------------------------
extern "C" void kernel_launch(void* const* d_in, const int* in_sizes, int n_in,
                              void* d_out, int out_size, void* d_ws, size_t ws_size,
                              hipStream_t stream) {
  const float* x0   = (const float*)d_in[0];
  const float* Wi_f = (const float*)d_in[1];
  const float* bi_f = (const float*)d_in[2];
  const float* Wh_f = (const float*)d_in[3];
  const float* bh_f = (const float*)d_in[4];
  const float* Wi_r = (const float*)d_in[5];
  const float* bi_r = (const float*)d_in[6];
  const float* Wh_r = (const float*)d_in[7];
  const float* bh_r = (const float*)d_in[8];
  const float* W1 = (const float*)d_in[9];
  const float* b1 = (const float*)d_in[10];
  const float* W2 = (const float*)d_in[11];
  const float* b2 = (const float*)d_in[12];
  const float* W3 = (const float*)d_in[13];
  const float* b3 = (const float*)d_in[14];
  float* out = (float*)d_out;

  char* ws = (char*)d_ws;
  u16* w1t   = (u16*)(ws + 0);         // 262144 B
  u16* w2t   = (u16*)(ws + 262144);    // 131072 B
  u16* w3t   = (u16*)(ws + 393216);    // 65536 B
  u16* wpack = (u16*)(ws + 458752);    // 1572864 B
  u16* x1    = (u16*)(ws + 2031616);   // 67108864 B

  hipLaunchKernelGGL(prep_wpack, dim3(3072), dim3(256), 0, stream,
                     Wi_f, Wh_f, Wi_r, Wh_r, wpack);
  hipLaunchKernelGGL(poison_x1, dim3(8192), dim3(256), 0, stream, (uint4*)x1);
  hipLaunchKernelGGL(prep_small, dim3(896), dim3(256), 0, stream,
                     W1, W2, W3, w1t, w2t, w3t);
  {
    void* params[7];
    params[0] = (void*)&x0;
    params[1] = (void*)&wpack;
    params[2] = (void*)&bi_f;
    params[3] = (void*)&bh_f;
    params[4] = (void*)&bi_r;
    params[5] = (void*)&bh_r;
    params[6] = (void*)&x1;
    hipLaunchCooperativeKernel((const void*)lstm_kernel, dim3(256), dim3(512),
                               params, 0, stream);
  }
  hipLaunchKernelGGL(mlp_kernel, dim3(512), dim3(512), 0, stream,
                     x1, w1t, w2t, w3t, b1, b2, b3, out);
}